// Round 10
// baseline (370.985 us; speedup 1.0000x reference)
//
#include <hip/hip_runtime.h>

typedef unsigned short u16;
typedef unsigned int u32;
typedef __bf16 bf16x8 __attribute__((ext_vector_type(8)));
typedef float floatx4 __attribute__((ext_vector_type(4)));

__device__ __forceinline__ u16 f2bf(float f) {
    u32 u = __float_as_uint(f);
    u = (u + 0x7FFFu + ((u >> 16) & 1u)) >> 16;
    return (u16)u;
}

__device__ __forceinline__ void gld_lds16(const u16* g, u16* l) {
    __builtin_amdgcn_global_load_lds(
        (const __attribute__((address_space(1))) u32*)g,
        (__attribute__((address_space(3))) u32*)l, 16, 0, 0);
}

// Exact-enough GELU: erf via Abramowitz-Stegun 7.1.26 (|err| < 1.5e-7).
__device__ __forceinline__ float gelu_exact(float v) {
    const float z = fabsf(v) * 0.70710678118f;
    const float t = __builtin_amdgcn_rcpf(1.0f + 0.3275911f * z);
    const float e = __builtin_amdgcn_exp2f(-z * z * 1.44269504f);
    float poly = 1.061405429f;
    poly = poly * t - 1.453152027f;
    poly = poly * t + 1.421413741f;
    poly = poly * t - 0.284496736f;
    poly = poly * t + 0.254829592f;
    float erfz = 1.0f - poly * t * e;
    erfz = copysignf(erfz, v);
    return 0.5f * v * (1.0f + erfz);
}

// ---------------------------------------------------------------------------
// Four 1024x1024 transposes + fp32->bf16 in one launch (z picks the matrix).
// ---------------------------------------------------------------------------
__global__ __launch_bounds__(256) void transpose_cvt4(
    const float* __restrict__ s0, const float* __restrict__ s1,
    const float* __restrict__ s2, const float* __restrict__ s3,
    u16* __restrict__ d0, u16* __restrict__ d1,
    u16* __restrict__ d2, u16* __restrict__ d3)
{
    __shared__ float t[32][33];
    const int z = blockIdx.z;
    const float* src = z == 0 ? s0 : (z == 1 ? s1 : (z == 2 ? s2 : s3));
    u16* dst = z == 0 ? d0 : (z == 1 ? d1 : (z == 2 ? d2 : d3));
    const int bm = blockIdx.x * 32, bk = blockIdx.y * 32;
    const int tx = threadIdx.x & 31, ty = threadIdx.x >> 5;
    #pragma unroll
    for (int i = ty; i < 32; i += 8)
        t[i][tx] = src[(long)(bk + i) * 1024 + bm + tx];
    __syncthreads();
    #pragma unroll
    for (int i = ty; i < 32; i += 8)
        dst[(long)(bm + i) * 1024 + bk + tx] = f2bf(t[tx][i]);
}

// ---------------------------------------------------------------------------
// Transpose + fp32->bf16: src K x M -> dst M x K.
// ---------------------------------------------------------------------------
__global__ __launch_bounds__(256) void transpose_cvt(
    const float* __restrict__ src, u16* __restrict__ dst, int K, int M)
{
    __shared__ float t[32][33];
    const int bm = blockIdx.x * 32, bk = blockIdx.y * 32;
    const int tx = threadIdx.x & 31, ty = threadIdx.x >> 5;
    #pragma unroll
    for (int i = ty; i < 32; i += 8)
        t[i][tx] = src[(long)(bk + i) * M + bm + tx];
    __syncthreads();
    #pragma unroll
    for (int i = ty; i < 32; i += 8)
        dst[(long)(bm + i) * K + bk + tx] = f2bf(t[tx][i]);
}

// ---------------------------------------------------------------------------
// LayerNorm over rows of 1024 fp32 -> bf16. One block per row.
// ---------------------------------------------------------------------------
__global__ __launch_bounds__(256) void ln_kernel(
    const float* __restrict__ x, const float* __restrict__ g,
    const float* __restrict__ bta, u16* __restrict__ out)
{
    const int row = blockIdx.x;
    const int tid = threadIdx.x;
    const float4 v = ((const float4*)(x + (long)row * 1024))[tid];
    float s  = v.x + v.y + v.z + v.w;
    float s2 = v.x*v.x + v.y*v.y + v.z*v.z + v.w*v.w;
    #pragma unroll
    for (int off = 1; off < 64; off <<= 1) {
        s  += __shfl_xor(s, off);
        s2 += __shfl_xor(s2, off);
    }
    __shared__ float red[8];
    const int wave = tid >> 6, lane = tid & 63;
    if (lane == 0) { red[wave] = s; red[4 + wave] = s2; }
    __syncthreads();
    s  = red[0] + red[1] + red[2] + red[3];
    s2 = red[4] + red[5] + red[6] + red[7];
    const float mu   = s * (1.0f / 1024.0f);
    const float var  = s2 * (1.0f / 1024.0f) - mu * mu;
    const float rstd = rsqrtf(var + 1e-5f);
    const int c = tid << 2;
    ushort4 o;
    o.x = f2bf((v.x - mu) * rstd * g[c + 0] + bta[c + 0]);
    o.y = f2bf((v.y - mu) * rstd * g[c + 1] + bta[c + 1]);
    o.z = f2bf((v.z - mu) * rstd * g[c + 2] + bta[c + 2]);
    o.w = f2bf((v.w - mu) * rstd * g[c + 3] + bta[c + 3]);
    ((ushort4*)(out + (long)row * 1024))[tid] = o;
}

// ---------------------------------------------------------------------------
// Split-K combine: out[i] += p1[i].
// ---------------------------------------------------------------------------
__global__ __launch_bounds__(256) void add_kernel(
    float* __restrict__ out, const float* __restrict__ p1)
{
    const int t = blockIdx.x * 256 + threadIdx.x;
    const float4 a = ((const float4*)out)[t];
    const float4 c = ((const float4*)p1)[t];
    float4 o;
    o.x = a.x + c.x;
    o.y = a.y + c.y;
    o.z = a.z + c.z;
    o.w = a.w + c.w;
    ((float4*)out)[t] = o;
}

// ---------------------------------------------------------------------------
// V transpose per (b,h): (bh, s=2048, d=64) -> (bh, d=64, s=2048), bf16.
// ---------------------------------------------------------------------------
__global__ __launch_bounds__(256) void vtrans_kernel(
    const u16* __restrict__ V, u16* __restrict__ Vt)
{
    __shared__ u16 t[64][72];
    const int bh = blockIdx.y, s0 = blockIdx.x << 6;
    const int tid = threadIdx.x;
    const long base = (long)bh * 2048 * 64;
    const int row = tid >> 2, seg = tid & 3;
    *(uint4*)&t[row][seg << 3] =
        *(const uint4*)(V + base + (long)(s0 + row) * 64 + (seg << 3));
    *(uint4*)&t[row][(seg + 4) << 3] =
        *(const uint4*)(V + base + (long)(s0 + row) * 64 + ((seg + 4) << 3));
    __syncthreads();
    #pragma unroll
    for (int half = 0; half < 2; ++half) {
        const int sl = (seg + (half << 2)) << 3;
        u16 tmp[8];
        #pragma unroll
        for (int j = 0; j < 8; ++j) tmp[j] = t[sl + j][row];
        *(uint4*)(Vt + base + (long)row * 2048 + s0 + sl) = *(uint4*)tmp;
    }
}

// ---------------------------------------------------------------------------
// 256x256-tile GEMM, BK=64, 8 waves (512 thr), dbuf LDS (128 KB, 1 blk/CU),
// early-issue staging, setprio around MFMA clusters.
// MODE 0: out bf16, fused QKV scatter; Q pre-scaled by 0.125*log2(e)
// MODE 2: out bf16 row-major, gelu(v+bias)
// ---------------------------------------------------------------------------
template<int MODE>
__global__ __launch_bounds__(512, 2) void gemm256_kernel(
    const u16* __restrict__ A, const u16* __restrict__ Bt,
    const float* __restrict__ bias0, const float* __restrict__ bias1,
    const float* __restrict__ bias2, void* __restrict__ outv, int K, int M)
{
    __shared__ u16 As[2][256 * 64];   // 32 KB each
    __shared__ u16 Bs[2][256 * 64];   // 32 KB each
    const int tid = threadIdx.x, lane = tid & 63, wave = tid >> 6;
    const int wr = wave >> 2, wc = wave & 3;
    const int lrow = lane & 15, quad = lane >> 4, sl = lrow & 7;

    const int nwg = gridDim.x * gridDim.y;
    const int lin = blockIdx.x + gridDim.x * blockIdx.y;
    const int wg  = (lin & 7) * (nwg >> 3) + (lin >> 3);
    const int bx  = wg % gridDim.x;
    const int by  = wg / gridDim.x;

    const long rowbase = (long)by * 256;
    const long colbase = (long)bx * 256;

    const u16* gA[4]; int lA[4];
    const u16* gB[4]; int lB[4];
    #pragma unroll
    for (int i = 0; i < 4; ++i) {
        const int cid = (i << 9) + tid;
        const int rl = cid >> 3, p = cid & 7, q = p ^ (rl & 7);
        gA[i] = A  + (rowbase + rl) * (long)K + (q << 3);
        gB[i] = Bt + (colbase + rl) * (long)K + (q << 3);
        lA[i] = rl * 64 + (p << 3);
        lB[i] = rl * 64 + (p << 3);
    }

    floatx4 acc[8][4];
    #pragma unroll
    for (int i = 0; i < 8; ++i)
        #pragma unroll
        for (int j = 0; j < 4; ++j)
            acc[i][j] = floatx4{0.f, 0.f, 0.f, 0.f};

    #pragma unroll
    for (int i = 0; i < 4; ++i) { gld_lds16(gA[i], As[0] + lA[i]); gA[i] += 64; }
    #pragma unroll
    for (int i = 0; i < 4; ++i) { gld_lds16(gB[i], Bs[0] + lB[i]); gB[i] += 64; }
    asm volatile("s_waitcnt vmcnt(0)" ::: "memory");
    __builtin_amdgcn_s_barrier();
    __builtin_amdgcn_sched_barrier(0);

    const int niter = K >> 6;
    int cur = 0;
    for (int t = 0; t < niter; ++t) {
        if (t + 1 < niter) {
            #pragma unroll
            for (int i = 0; i < 4; ++i) { gld_lds16(gA[i], As[cur ^ 1] + lA[i]); gA[i] += 64; }
            #pragma unroll
            for (int i = 0; i < 4; ++i) { gld_lds16(gB[i], Bs[cur ^ 1] + lB[i]); gB[i] += 64; }
        }

        const u16* as = As[cur];
        const u16* bs = Bs[cur];

        bf16x8 bfr[4][2];
        #pragma unroll
        for (int ns = 0; ns < 4; ++ns)
            #pragma unroll
            for (int kc = 0; kc < 2; ++kc)
                bfr[ns][kc] = *(const bf16x8*)
                    &bs[((wc << 6) + (ns << 4) + lrow) * 64 + ((((kc << 2) + quad) ^ sl) << 3)];

        #pragma unroll
        for (int p = 0; p < 4; ++p) {
            bf16x8 af[2][2];
            #pragma unroll
            for (int m = 0; m < 2; ++m)
                #pragma unroll
                for (int kc = 0; kc < 2; ++kc)
                    af[m][kc] = *(const bf16x8*)
                        &as[((wr << 7) + ((p * 2 + m) << 4) + lrow) * 64 + ((((kc << 2) + quad) ^ sl) << 3)];
            __builtin_amdgcn_s_setprio(1);
            #pragma unroll
            for (int kc = 0; kc < 2; ++kc)
                #pragma unroll
                for (int m = 0; m < 2; ++m)
                    #pragma unroll
                    for (int ns = 0; ns < 4; ++ns)
                        acc[p * 2 + m][ns] = __builtin_amdgcn_mfma_f32_16x16x32_bf16(
                            af[m][kc], bfr[ns][kc], acc[p * 2 + m][ns], 0, 0, 0);
            __builtin_amdgcn_s_setprio(0);
        }

        asm volatile("s_waitcnt lgkmcnt(0)" ::: "memory");
        asm volatile("s_waitcnt vmcnt(0)" ::: "memory");
        __builtin_amdgcn_s_barrier();
        __builtin_amdgcn_sched_barrier(0);
        cur ^= 1;
    }

    #pragma unroll
    for (int ms = 0; ms < 8; ++ms) {
        #pragma unroll
        for (int ns = 0; ns < 4; ++ns) {
            const long col = colbase + (wc << 6) + (ns << 4) + lrow;
            float bv;
            if constexpr (MODE == 0) {
                const int which = (int)(col >> 10);
                const float* bp = which == 0 ? bias0 : (which == 1 ? bias1 : bias2);
                bv = bp[col & 1023];
            } else {
                bv = bias0[col];
            }
            #pragma unroll
            for (int r = 0; r < 4; ++r) {
                const long row = rowbase + (wr << 7) + (ms << 4) + (quad << 2) + r;
                float v = acc[ms][ns][r] + bv;
                if constexpr (MODE == 0) {
                    const long which = col >> 10;
                    if (which == 0) v *= 0.18033688f;   // 0.125*log2(e) into Q
                    const long b = row >> 11, s = row & 2047;
                    const long h = (col >> 6) & 15, d = col & 63;
                    ((u16*)outv)[which * 4194304 + (((b << 4) + h) * 2048 + s) * 64 + d] = f2bf(v);
                } else {
                    ((u16*)outv)[row * M + col] = f2bf(gelu_exact(v));
                }
            }
        }
    }
}

// ---------------------------------------------------------------------------
// FF2: 128x128-tile split-K=2, 8 waves x (64x32 output) = 512 threads.
// z=0 -> out (+bias+res folded), z=1 -> part1; add_kernel combines.
// ---------------------------------------------------------------------------
__global__ __launch_bounds__(512, 2) void gemm_ff2_kernel(
    const u16* __restrict__ A, const u16* __restrict__ Bt,
    const float* __restrict__ bias0, const float* __restrict__ res,
    float* __restrict__ part1, float* __restrict__ out, int K, int M)
{
    __shared__ u16 As[2][128 * 64];   // 16 KB each
    __shared__ u16 Bs[2][128 * 64];   // 16 KB each
    const int tid = threadIdx.x, lane = tid & 63, wave = tid >> 6;
    const int wr = wave >> 2, wc = wave & 3;
    const int lrow = lane & 15, quad = lane >> 4, sl = lrow & 7;

    const int nwg = gridDim.x * gridDim.y * gridDim.z;
    const int lin = blockIdx.x + gridDim.x * (blockIdx.y + gridDim.y * blockIdx.z);
    const int wg  = (lin & 7) * (nwg >> 3) + (lin >> 3);
    const int bx  = wg % gridDim.x;
    const int rest = wg / gridDim.x;
    const int by  = rest % gridDim.y;
    const int bz  = rest / gridDim.y;

    const long rowbase = (long)by * 128;
    const long colbase = (long)bx * 128;
    const int kstart = bz * (K >> 1);
    const int kend   = kstart + (K >> 1);

    const u16* gA[2]; int lA[2];
    const u16* gB[2]; int lB[2];
    #pragma unroll
    for (int i = 0; i < 2; ++i) {
        const int cid = (i << 9) + tid;
        const int rl = cid >> 3, p = cid & 7, q = p ^ (rl & 7);
        gA[i] = A  + (rowbase + rl) * (long)K + kstart + (q << 3);
        gB[i] = Bt + (colbase + rl) * (long)K + kstart + (q << 3);
        lA[i] = rl * 64 + (p << 3);
        lB[i] = rl * 64 + (p << 3);
    }

    floatx4 acc[4][2];
    #pragma unroll
    for (int i = 0; i < 4; ++i)
        #pragma unroll
        for (int j = 0; j < 2; ++j)
            acc[i][j] = floatx4{0.f, 0.f, 0.f, 0.f};

    #pragma unroll
    for (int i = 0; i < 2; ++i) { gld_lds16(gA[i], As[0] + lA[i]); gA[i] += 64; }
    #pragma unroll
    for (int i = 0; i < 2; ++i) { gld_lds16(gB[i], Bs[0] + lB[i]); gB[i] += 64; }
    asm volatile("s_waitcnt vmcnt(0)" ::: "memory");
    __builtin_amdgcn_s_barrier();
    __builtin_amdgcn_sched_barrier(0);

    const int niter = (kend - kstart) >> 6;
    int cur = 0;
    for (int t = 0; t < niter; ++t) {
        if (t + 1 < niter) {
            #pragma unroll
            for (int i = 0; i < 2; ++i) { gld_lds16(gA[i], As[cur ^ 1] + lA[i]); gA[i] += 64; }
            #pragma unroll
            for (int i = 0; i < 2; ++i) { gld_lds16(gB[i], Bs[cur ^ 1] + lB[i]); gB[i] += 64; }
        }

        const u16* as = As[cur];
        const u16* bs = Bs[cur];

        bf16x8 bfr[2][2], af[4][2];
        #pragma unroll
        for (int ns = 0; ns < 2; ++ns)
            #pragma unroll
            for (int kc = 0; kc < 2; ++kc)
                bfr[ns][kc] = *(const bf16x8*)
                    &bs[((wc << 5) + (ns << 4) + lrow) * 64 + ((((kc << 2) + quad) ^ sl) << 3)];
        #pragma unroll
        for (int m = 0; m < 4; ++m)
            #pragma unroll
            for (int kc = 0; kc < 2; ++kc)
                af[m][kc] = *(const bf16x8*)
                    &as[((wr << 6) + (m << 4) + lrow) * 64 + ((((kc << 2) + quad) ^ sl) << 3)];

        __builtin_amdgcn_s_setprio(1);
        #pragma unroll
        for (int kc = 0; kc < 2; ++kc)
            #pragma unroll
            for (int m = 0; m < 4; ++m)
                #pragma unroll
                for (int ns = 0; ns < 2; ++ns)
                    acc[m][ns] = __builtin_amdgcn_mfma_f32_16x16x32_bf16(
                        af[m][kc], bfr[ns][kc], acc[m][ns], 0, 0, 0);
        __builtin_amdgcn_s_setprio(0);

        asm volatile("s_waitcnt lgkmcnt(0)" ::: "memory");
        asm volatile("s_waitcnt vmcnt(0)" ::: "memory");
        __builtin_amdgcn_s_barrier();
        __builtin_amdgcn_sched_barrier(0);
        cur ^= 1;
    }

    float* tgt = bz ? part1 : out;
    #pragma unroll
    for (int m = 0; m < 4; ++m) {
        #pragma unroll
        for (int ns = 0; ns < 2; ++ns) {
            const long col = colbase + (wc << 5) + (ns << 4) + lrow;
            #pragma unroll
            for (int r = 0; r < 4; ++r) {
                const long row = rowbase + (wr << 6) + (m << 4) + (quad << 2) + r;
                const long idx = row * M + col;
                float v = acc[m][ns][r];
                if (bz == 0)
                    tgt[idx] = v + bias0[col] + res[idx];  // fold b2 + residual
                else
                    tgt[idx] = v;
            }
        }
    }
}

// ---------------------------------------------------------------------------
// 128x64 GEMM (O-proj): single-buffer 2-phase, 24 KB LDS -> high TLP.
// out fp32 row-major, +bias +res.
// ---------------------------------------------------------------------------
__global__ __launch_bounds__(256) void gemm_oproj_kernel(
    const u16* __restrict__ A, const u16* __restrict__ Bt,
    const float* __restrict__ bias0, const float* __restrict__ res,
    float* __restrict__ out, int K, int M)
{
    constexpr int MS = 2, NIB = 2;
    __shared__ u16 As[128 * 64];
    __shared__ u16 Bs[64 * 64];
    const int tid = threadIdx.x, lane = tid & 63, wave = tid >> 6;
    const int wm = wave << 5, wn = 0;
    const int lrow = lane & 15, quad = lane >> 4;
    const int sl = lrow & 7;

    const int nwg = gridDim.x * gridDim.y;
    const int lin = blockIdx.x + gridDim.x * blockIdx.y;
    const int wg  = (lin & 7) * (nwg >> 3) + (lin >> 3);
    const int bx  = wg % gridDim.x;
    const int by  = wg / gridDim.x;

    const long rowbase = (long)by * 128;
    const long colbase = (long)bx * 64;

    const u16* gA[4]; int lA[4];
    #pragma unroll
    for (int i = 0; i < 4; ++i) {
        const int cid = (i << 6) + lane;
        const int rl = cid >> 3, p = cid & 7, q = p ^ (rl & 7);
        gA[i] = A + (rowbase + (wave << 5) + rl) * (long)K + (q << 3);
        lA[i] = ((wave << 5) + rl) * 64 + (p << 3);
    }
    const u16* gB[NIB]; int lB[NIB];
    #pragma unroll
    for (int i = 0; i < NIB; ++i) {
        const int cid = (i << 6) + lane;
        const int rl = cid >> 3, p = cid & 7, q = p ^ (rl & 7);
        gB[i] = Bt + (colbase + (wave << 4) + rl) * (long)K + (q << 3);
        lB[i] = ((wave << 4) + rl) * 64 + (p << 3);
    }

    floatx4 acc[MS][4];
    #pragma unroll
    for (int i = 0; i < MS; ++i)
        #pragma unroll
        for (int j = 0; j < 4; ++j)
            acc[i][j] = floatx4{0.f, 0.f, 0.f, 0.f};

    for (int k0 = 0; k0 < K; k0 += 64) {
        __syncthreads();
        #pragma unroll
        for (int i = 0; i < 4; ++i) { gld_lds16(gA[i], As + lA[i]); gA[i] += 64; }
        #pragma unroll
        for (int i = 0; i < NIB; ++i) { gld_lds16(gB[i], Bs + lB[i]); gB[i] += 64; }
        __syncthreads();
        #pragma unroll
        for (int kc = 0; kc < 2; ++kc) {
            const int ph = (((kc << 2) + quad) ^ sl) << 3;
            bf16x8 af[MS], bf[4];
            #pragma unroll
            for (int ms = 0; ms < MS; ++ms)
                af[ms] = *(const bf16x8*)&As[(wm + (ms << 4) + lrow) * 64 + ph];
            #pragma unroll
            for (int ns = 0; ns < 4; ++ns)
                bf[ns] = *(const bf16x8*)&Bs[(wn + (ns << 4) + lrow) * 64 + ph];
            #pragma unroll
            for (int ms = 0; ms < MS; ++ms)
                #pragma unroll
                for (int ns = 0; ns < 4; ++ns)
                    acc[ms][ns] = __builtin_amdgcn_mfma_f32_16x16x32_bf16(
                        af[ms], bf[ns], acc[ms][ns], 0, 0, 0);
        }
    }

    #pragma unroll
    for (int ms = 0; ms < MS; ++ms) {
        #pragma unroll
        for (int ns = 0; ns < 4; ++ns) {
            const long col = colbase + wn + (ns << 4) + lrow;
            const float bv = bias0[col];
            #pragma unroll
            for (int r = 0; r < 4; ++r) {
                const long row = rowbase + wm + (ms << 4) + (quad << 2) + r;
                const long idx = row * M + col;
                out[idx] = acc[ms][ns][r] + bv + res[idx];
            }
        }
    }
}

// ---------------------------------------------------------------------------
// Flash attention v10: split-KV=2. Static-max softmax means oacc and lr are
// PLAIN SUMS over keys -> KV halves are independent. 1024 blocks (32 bh x
// 16 qt x 2 kz) writes fp32 partials po[kz] + row-sums l[kz]; a slim
// combine kernel normalizes. Occupancy: 2 -> 3 blocks/CU (LDS-capped).
// XCD swizzle: 128-block chunks keep 4 heads per XCD.
// ---------------------------------------------------------------------------
__global__ __launch_bounds__(512) void attn_kernel(
    const u16* __restrict__ Q, const u16* __restrict__ Kp,
    const u16* __restrict__ Vt, float* __restrict__ PO,
    float* __restrict__ LP)
{
    __shared__ u16 Ks[2][4096];       // 16 KB (dbuf)
    __shared__ u16 Vs[2][4096];       // 16 KB (dbuf)
    __shared__ u16 Ps[8][16][72];     // 18 KB
    const int tid = threadIdx.x, lane = tid & 63, wave = tid >> 6;
    const int lrow = lane & 15, quad = lane >> 4;

    // XCD-bijective swizzle: 1024 blocks -> 8 chunks of 128 (4 heads each).
    const int lin = blockIdx.x;
    const int nl  = ((lin & 7) << 7) + (lin >> 3);
    const int bh  = nl >> 5;
    const int qt  = (nl >> 1) & 15;
    const int kz  = nl & 1;
    const long kvbase = (long)bh * 2048 * 64;
    const int qbase = (qt << 7) + (wave << 4);

    // Staging: wave role split. c = quarter index (16 rows of the 64-row tile).
    const int srow = lane >> 3;
    const int schunk = (lane & 7) ^ srow;
    const int c = wave & 3;
    const bool isV = wave >= 4;
    const int lofs = c << 10;
    const u16* g0 = isV
        ? (Vt + kvbase + (long)(((c << 4) + srow) * 2048 + (kz << 10) + (schunk << 3)))
        : (Kp + kvbase + (long)(kz << 16) + (long)(((c << 4) + srow) * 64 + (schunk << 3)));
    const u16* g1 = g0 + (isV ? 8 * 2048 : 8 * 64);
    const int gstep = isV ? 64 : 4096;
    u16* lb0 = isV ? &Vs[0][lofs] : &Ks[0][lofs];
    u16* lb1 = isV ? &Vs[1][lofs] : &Ks[1][lofs];

    bf16x8 qf[2];
    #pragma unroll
    for (int h = 0; h < 2; ++h)
        qf[h] = *(const bf16x8*)(Q + kvbase +
            (long)(qbase + lrow) * 64 + (quad << 3) + (h << 5));

    int aoff[4][2];
    #pragma unroll
    for (int ns = 0; ns < 4; ++ns)
        #pragma unroll
        for (int h = 0; h < 2; ++h)
            aoff[ns][h] = ((ns << 4) + lrow) * 64 +
                          (((quad + (h << 2)) ^ (lrow & 7)) << 3);

    floatx4 oacc[4];
    #pragma unroll
    for (int ns = 0; ns < 4; ++ns)
        oacc[ns] = floatx4{0.f, 0.f, 0.f, 0.f};
    float lr = 0.f;

    gld_lds16(g0, lb0);
    gld_lds16(g1, lb0 + 512);
    g0 += gstep; g1 += gstep;

    for (int it = 0; it < 16; ++it) {
        const int cur = it & 1;
        __syncthreads();
        if (it < 15) {
            u16* dst = cur ? lb0 : lb1;
            gld_lds16(g0, dst);
            gld_lds16(g1, dst + 512);
            g0 += gstep; g1 += gstep;
        }
        const u16* ks = &Ks[cur][0];
        const u16* vs = &Vs[cur][0];

        floatx4 st[4];
        __builtin_amdgcn_s_setprio(1);
        #pragma unroll
        for (int ns = 0; ns < 4; ++ns) {
            const bf16x8 af0 = *(const bf16x8*)&ks[aoff[ns][0]];
            const bf16x8 af1 = *(const bf16x8*)&ks[aoff[ns][1]];
            floatx4 z = floatx4{0.f, 0.f, 0.f, 0.f};
            st[ns] = __builtin_amdgcn_mfma_f32_16x16x32_bf16(af0, qf[0], z, 0, 0, 0);
            st[ns] = __builtin_amdgcn_mfma_f32_16x16x32_bf16(af1, qf[1], st[ns], 0, 0, 0);
        }
        __builtin_amdgcn_s_setprio(0);

        float rs = 0.f;
        #pragma unroll
        for (int ns = 0; ns < 4; ++ns) {
            const float p0 = __builtin_amdgcn_exp2f(st[ns][0]);
            const float p1 = __builtin_amdgcn_exp2f(st[ns][1]);
            const float p2 = __builtin_amdgcn_exp2f(st[ns][2]);
            const float p3 = __builtin_amdgcn_exp2f(st[ns][3]);
            rs += (p0 + p1) + (p2 + p3);
            uint2 w;
            w.x = __builtin_amdgcn_perm(__float_as_uint(p1) + 0x8000u,
                                        __float_as_uint(p0) + 0x8000u, 0x07060302u);
            w.y = __builtin_amdgcn_perm(__float_as_uint(p3) + 0x8000u,
                                        __float_as_uint(p2) + 0x8000u, 0x07060302u);
            *(uint2*)&Ps[wave][lrow][(ns << 4) + (quad << 2)] = w;
        }
        rs += __shfl_xor(rs, 16);
        rs += __shfl_xor(rs, 32);
        lr += rs;
        const bf16x8 pf0 = *(const bf16x8*)&Ps[wave][lrow][quad << 3];
        const bf16x8 pf1 = *(const bf16x8*)&Ps[wave][lrow][(quad << 3) + 32];

        __builtin_amdgcn_s_setprio(1);
        #pragma unroll
        for (int ns = 0; ns < 4; ++ns) {
            const bf16x8 vf0 = *(const bf16x8*)&vs[aoff[ns][0]];
            const bf16x8 vf1 = *(const bf16x8*)&vs[aoff[ns][1]];
            oacc[ns] = __builtin_amdgcn_mfma_f32_16x16x32_bf16(pf0, vf0, oacc[ns], 0, 0, 0);
            oacc[ns] = __builtin_amdgcn_mfma_f32_16x16x32_bf16(pf1, vf1, oacc[ns], 0, 0, 0);
        }
        __builtin_amdgcn_s_setprio(0);
    }

    // Partial outputs (un-normalized) + partial row sums.
    float* po = PO + (long)kz * 4194304 + (long)bh * 2048 * 64;
    #pragma unroll
    for (int ns = 0; ns < 4; ++ns)
        #pragma unroll
        for (int r = 0; r < 4; ++r) {
            const int q = qbase + (quad << 2) + r;
            po[(long)q * 64 + (ns << 4) + lrow] = oacc[ns][r];
        }
    if (quad == 0)
        LP[kz * 65536 + bh * 2048 + qbase + lrow] = lr;
}

// ---------------------------------------------------------------------------
// Attn split-KV combine: O = (po0 + po1) / (l0 + l1) -> bf16 h1 layout.
// ---------------------------------------------------------------------------
__global__ __launch_bounds__(256) void attn_combine_kernel(
    const float* __restrict__ PO, const float* __restrict__ LP,
    u16* __restrict__ O)
{
    const int tid = threadIdx.x;
    const int row = blockIdx.x * 16 + (tid >> 4);   // bh*2048+q, 0..65535
    const int d4  = (tid & 15) << 2;
    const float4 a = *(const float4*)(PO + (long)row * 64 + d4);
    const float4 b = *(const float4*)(PO + 4194304 + (long)row * 64 + d4);
    const float rinv = 1.0f / (LP[row] + LP[65536 + row]);
    const int bh = row >> 11, q = row & 2047;
    const int bb = bh >> 4, h = bh & 15;
    ushort4 o;
    o.x = f2bf((a.x + b.x) * rinv);
    o.y = f2bf((a.y + b.y) * rinv);
    o.z = f2bf((a.z + b.z) * rinv);
    o.w = f2bf((a.w + b.w) * rinv);
    *(ushort4*)(O + ((long)(bb * 2048 + q) * 1024 + (h << 6) + d4)) = o;
}

// ---------------------------------------------------------------------------
// Host launcher
// ---------------------------------------------------------------------------
extern "C" void kernel_launch(void* const* d_in, const int* in_sizes, int n_in,
                              void* d_out, int out_size, void* d_ws, size_t ws_size,
                              hipStream_t stream)
{
    const float* x     = (const float*)d_in[0];
    const float* ln1_g = (const float*)d_in[1];
    const float* ln1_b = (const float*)d_in[2];
    const float* wq    = (const float*)d_in[3];
    const float* bq    = (const float*)d_in[4];
    const float* wk    = (const float*)d_in[5];
    const float* bk    = (const float*)d_in[6];
    const float* wv    = (const float*)d_in[7];
    const float* bv    = (const float*)d_in[8];
    const float* wo    = (const float*)d_in[9];
    const float* bo    = (const float*)d_in[10];
    const float* w1    = (const float*)d_in[11];
    const float* b1    = (const float*)d_in[12];
    const float* w2    = (const float*)d_in[13];
    const float* b2    = (const float*)d_in[14];
    const float* ln2_g = (const float*)d_in[15];
    const float* ln2_b = (const float*)d_in[16];
    float* out = (float*)d_out;

    char* w = (char*)d_ws;
    const size_t MB = 1024 * 1024;
    u16*   wqkvt = (u16*)(w + 0);        // [0,6) MB
    u16*   wot   = (u16*)(w + 6  * MB);  // [6,8)
    u16*   w1t   = (u16*)(w + 8  * MB);  // [8,16)
    u16*   w2t   = (u16*)(w + 16 * MB);  // [16,24)
    u16*   h1    = (u16*)(w + 24 * MB);  // [24,32): ln1 / attn-out / ln2
    u16*   qkvb  = (u16*)(w + 32 * MB);  // [32,56): Q|K|V (bh,s,d)
    u16*   vtb   = (u16*)(w + 56 * MB);  // [56,64): V^T (bh,d,s)
    float* x1    = (float*)(w + 64 * MB);// [64,80): fp32 residual-1
    float* part1 = (float*)(w + 80 * MB);// [80,96): FF2 split-K partial z=1
    float* po    = (float*)(w + 64 * MB);// [64,96): attn partials (dead x1/part1)
    float* lp    = (float*)(w + 96 * MB);// [96,96.5): attn partial row sums
    u16*   ffb   = (u16*)(w + 32 * MB);  // [32,64): FF hidden (reuses qkv/vtb)
    u16*   qb = qkvb;
    u16*   kb = qkvb + 4194304;
    u16*   vb = qkvb + 8388608;

    transpose_cvt4<<<dim3(32, 32, 4), 256, 0, stream>>>(
        wq, wk, wv, wo, wqkvt, wqkvt + 1048576, wqkvt + 2097152, wot);
    transpose_cvt<<<dim3(128, 32), 256, 0, stream>>>(w1, w1t, 1024, 4096);
    transpose_cvt<<<dim3(32, 128), 256, 0, stream>>>(w2, w2t, 4096, 1024);

    ln_kernel<<<4096, 256, 0, stream>>>(x, ln1_g, ln1_b, h1);

    // QKV: 4096x3072, K=1024. 256^2 tiles -> 192 blocks.
    gemm256_kernel<0><<<dim3(12, 16), 512, 0, stream>>>(
        h1, wqkvt, bq, bk, bv, qkvb, 1024, 3072);

    vtrans_kernel<<<dim3(32, 32), 256, 0, stream>>>(vb, vtb);

    // Attention: split-KV=2 -> 1024 blocks, partials + combine.
    attn_kernel<<<dim3(1024), 512, 0, stream>>>(qb, kb, vtb, po, lp);
    attn_combine_kernel<<<dim3(4096), 256, 0, stream>>>(po, lp, h1);

    // O-proj: 4096x1024, K=1024. 128x64 single-buffer, high TLP.
    gemm_oproj_kernel<<<dim3(16, 32), 256, 0, stream>>>(
        h1, wot, bo, x, x1, 1024, 1024);

    ln_kernel<<<4096, 256, 0, stream>>>(x1, ln2_g, ln2_b, h1);

    // FF1: 4096x4096, K=1024. 256^2 tiles -> 256 blocks = 1/CU.
    gemm256_kernel<2><<<dim3(16, 16), 512, 0, stream>>>(
        h1, w1t, b1, nullptr, nullptr, ffb, 1024, 4096);

    // FF2: 4096x1024, K=4096. 128^2 8-wave dbuf split-K=2 -> 512 blocks.
    gemm_ff2_kernel<<<dim3(8, 32, 2), 512, 0, stream>>>(
        ffb, w2t, b2, x1, part1, out, 4096, 1024);

    add_kernel<<<4096, 256, 0, stream>>>(out, part1);
}

// Round 11
// 347.455 us; speedup vs baseline: 1.0677x; 1.0677x over previous
//
#include <hip/hip_runtime.h>

typedef unsigned short u16;
typedef unsigned int u32;
typedef __bf16 bf16x8 __attribute__((ext_vector_type(8)));
typedef float floatx4 __attribute__((ext_vector_type(4)));

__device__ __forceinline__ u16 f2bf(float f) {
    u32 u = __float_as_uint(f);
    u = (u + 0x7FFFu + ((u >> 16) & 1u)) >> 16;
    return (u16)u;
}

__device__ __forceinline__ void gld_lds16(const u16* g, u16* l) {
    __builtin_amdgcn_global_load_lds(
        (const __attribute__((address_space(1))) u32*)g,
        (__attribute__((address_space(3))) u32*)l, 16, 0, 0);
}

// Exact-enough GELU: erf via Abramowitz-Stegun 7.1.26 (|err| < 1.5e-7).
__device__ __forceinline__ float gelu_exact(float v) {
    const float z = fabsf(v) * 0.70710678118f;
    const float t = __builtin_amdgcn_rcpf(1.0f + 0.3275911f * z);
    const float e = __builtin_amdgcn_exp2f(-z * z * 1.44269504f);
    float poly = 1.061405429f;
    poly = poly * t - 1.453152027f;
    poly = poly * t + 1.421413741f;
    poly = poly * t - 0.284496736f;
    poly = poly * t + 0.254829592f;
    float erfz = 1.0f - poly * t * e;
    erfz = copysignf(erfz, v);
    return 0.5f * v * (1.0f + erfz);
}

// ---------------------------------------------------------------------------
// Four 1024x1024 transposes + fp32->bf16 in one launch (z picks the matrix).
// ---------------------------------------------------------------------------
__global__ __launch_bounds__(256) void transpose_cvt4(
    const float* __restrict__ s0, const float* __restrict__ s1,
    const float* __restrict__ s2, const float* __restrict__ s3,
    u16* __restrict__ d0, u16* __restrict__ d1,
    u16* __restrict__ d2, u16* __restrict__ d3)
{
    __shared__ float t[32][33];
    const int z = blockIdx.z;
    const float* src = z == 0 ? s0 : (z == 1 ? s1 : (z == 2 ? s2 : s3));
    u16* dst = z == 0 ? d0 : (z == 1 ? d1 : (z == 2 ? d2 : d3));
    const int bm = blockIdx.x * 32, bk = blockIdx.y * 32;
    const int tx = threadIdx.x & 31, ty = threadIdx.x >> 5;
    #pragma unroll
    for (int i = ty; i < 32; i += 8)
        t[i][tx] = src[(long)(bk + i) * 1024 + bm + tx];
    __syncthreads();
    #pragma unroll
    for (int i = ty; i < 32; i += 8)
        dst[(long)(bm + i) * 1024 + bk + tx] = f2bf(t[tx][i]);
}

// ---------------------------------------------------------------------------
// Transpose + fp32->bf16: src K x M -> dst M x K.
// ---------------------------------------------------------------------------
__global__ __launch_bounds__(256) void transpose_cvt(
    const float* __restrict__ src, u16* __restrict__ dst, int K, int M)
{
    __shared__ float t[32][33];
    const int bm = blockIdx.x * 32, bk = blockIdx.y * 32;
    const int tx = threadIdx.x & 31, ty = threadIdx.x >> 5;
    #pragma unroll
    for (int i = ty; i < 32; i += 8)
        t[i][tx] = src[(long)(bk + i) * M + bm + tx];
    __syncthreads();
    #pragma unroll
    for (int i = ty; i < 32; i += 8)
        dst[(long)(bm + i) * K + bk + tx] = f2bf(t[tx][i]);
}

// ---------------------------------------------------------------------------
// LayerNorm over rows of 1024 fp32 -> bf16. One block per row.
// ---------------------------------------------------------------------------
__global__ __launch_bounds__(256) void ln_kernel(
    const float* __restrict__ x, const float* __restrict__ g,
    const float* __restrict__ bta, u16* __restrict__ out)
{
    const int row = blockIdx.x;
    const int tid = threadIdx.x;
    const float4 v = ((const float4*)(x + (long)row * 1024))[tid];
    float s  = v.x + v.y + v.z + v.w;
    float s2 = v.x*v.x + v.y*v.y + v.z*v.z + v.w*v.w;
    #pragma unroll
    for (int off = 1; off < 64; off <<= 1) {
        s  += __shfl_xor(s, off);
        s2 += __shfl_xor(s2, off);
    }
    __shared__ float red[8];
    const int wave = tid >> 6, lane = tid & 63;
    if (lane == 0) { red[wave] = s; red[4 + wave] = s2; }
    __syncthreads();
    s  = red[0] + red[1] + red[2] + red[3];
    s2 = red[4] + red[5] + red[6] + red[7];
    const float mu   = s * (1.0f / 1024.0f);
    const float var  = s2 * (1.0f / 1024.0f) - mu * mu;
    const float rstd = rsqrtf(var + 1e-5f);
    const int c = tid << 2;
    ushort4 o;
    o.x = f2bf((v.x - mu) * rstd * g[c + 0] + bta[c + 0]);
    o.y = f2bf((v.y - mu) * rstd * g[c + 1] + bta[c + 1]);
    o.z = f2bf((v.z - mu) * rstd * g[c + 2] + bta[c + 2]);
    o.w = f2bf((v.w - mu) * rstd * g[c + 3] + bta[c + 3]);
    ((ushort4*)(out + (long)row * 1024))[tid] = o;
}

// ---------------------------------------------------------------------------
// Split-K combine: out[i] += p1[i].
// ---------------------------------------------------------------------------
__global__ __launch_bounds__(256) void add_kernel(
    float* __restrict__ out, const float* __restrict__ p1)
{
    const int t = blockIdx.x * 256 + threadIdx.x;
    const float4 a = ((const float4*)out)[t];
    const float4 c = ((const float4*)p1)[t];
    float4 o;
    o.x = a.x + c.x;
    o.y = a.y + c.y;
    o.z = a.z + c.z;
    o.w = a.w + c.w;
    ((float4*)out)[t] = o;
}

// ---------------------------------------------------------------------------
// V transpose per (b,h): (bh, s=2048, d=64) -> (bh, d=64, s=2048), bf16.
// ---------------------------------------------------------------------------
__global__ __launch_bounds__(256) void vtrans_kernel(
    const u16* __restrict__ V, u16* __restrict__ Vt)
{
    __shared__ u16 t[64][72];
    const int bh = blockIdx.y, s0 = blockIdx.x << 6;
    const int tid = threadIdx.x;
    const long base = (long)bh * 2048 * 64;
    const int row = tid >> 2, seg = tid & 3;
    *(uint4*)&t[row][seg << 3] =
        *(const uint4*)(V + base + (long)(s0 + row) * 64 + (seg << 3));
    *(uint4*)&t[row][(seg + 4) << 3] =
        *(const uint4*)(V + base + (long)(s0 + row) * 64 + ((seg + 4) << 3));
    __syncthreads();
    #pragma unroll
    for (int half = 0; half < 2; ++half) {
        const int sl = (seg + (half << 2)) << 3;
        u16 tmp[8];
        #pragma unroll
        for (int j = 0; j < 8; ++j) tmp[j] = t[sl + j][row];
        *(uint4*)(Vt + base + (long)row * 2048 + s0 + sl) = *(uint4*)tmp;
    }
}

// ---------------------------------------------------------------------------
// 256x256-tile GEMM, BK=64, 8 waves (512 thr), dbuf LDS (128 KB, 1 blk/CU),
// early-issue staging, setprio around MFMA clusters.
// MODE 0: out bf16, fused QKV scatter; Q pre-scaled by 0.125*log2(e)
// MODE 2: out bf16 row-major, gelu(v+bias)
// ---------------------------------------------------------------------------
template<int MODE>
__global__ __launch_bounds__(512, 2) void gemm256_kernel(
    const u16* __restrict__ A, const u16* __restrict__ Bt,
    const float* __restrict__ bias0, const float* __restrict__ bias1,
    const float* __restrict__ bias2, void* __restrict__ outv, int K, int M)
{
    __shared__ u16 As[2][256 * 64];   // 32 KB each
    __shared__ u16 Bs[2][256 * 64];   // 32 KB each
    const int tid = threadIdx.x, lane = tid & 63, wave = tid >> 6;
    const int wr = wave >> 2, wc = wave & 3;
    const int lrow = lane & 15, quad = lane >> 4, sl = lrow & 7;

    const int nwg = gridDim.x * gridDim.y;
    const int lin = blockIdx.x + gridDim.x * blockIdx.y;
    const int wg  = (lin & 7) * (nwg >> 3) + (lin >> 3);
    const int bx  = wg % gridDim.x;
    const int by  = wg / gridDim.x;

    const long rowbase = (long)by * 256;
    const long colbase = (long)bx * 256;

    const u16* gA[4]; int lA[4];
    const u16* gB[4]; int lB[4];
    #pragma unroll
    for (int i = 0; i < 4; ++i) {
        const int cid = (i << 9) + tid;
        const int rl = cid >> 3, p = cid & 7, q = p ^ (rl & 7);
        gA[i] = A  + (rowbase + rl) * (long)K + (q << 3);
        gB[i] = Bt + (colbase + rl) * (long)K + (q << 3);
        lA[i] = rl * 64 + (p << 3);
        lB[i] = rl * 64 + (p << 3);
    }

    floatx4 acc[8][4];
    #pragma unroll
    for (int i = 0; i < 8; ++i)
        #pragma unroll
        for (int j = 0; j < 4; ++j)
            acc[i][j] = floatx4{0.f, 0.f, 0.f, 0.f};

    #pragma unroll
    for (int i = 0; i < 4; ++i) { gld_lds16(gA[i], As[0] + lA[i]); gA[i] += 64; }
    #pragma unroll
    for (int i = 0; i < 4; ++i) { gld_lds16(gB[i], Bs[0] + lB[i]); gB[i] += 64; }
    asm volatile("s_waitcnt vmcnt(0)" ::: "memory");
    __builtin_amdgcn_s_barrier();
    __builtin_amdgcn_sched_barrier(0);

    const int niter = K >> 6;
    int cur = 0;
    for (int t = 0; t < niter; ++t) {
        if (t + 1 < niter) {
            #pragma unroll
            for (int i = 0; i < 4; ++i) { gld_lds16(gA[i], As[cur ^ 1] + lA[i]); gA[i] += 64; }
            #pragma unroll
            for (int i = 0; i < 4; ++i) { gld_lds16(gB[i], Bs[cur ^ 1] + lB[i]); gB[i] += 64; }
        }

        const u16* as = As[cur];
        const u16* bs = Bs[cur];

        bf16x8 bfr[4][2];
        #pragma unroll
        for (int ns = 0; ns < 4; ++ns)
            #pragma unroll
            for (int kc = 0; kc < 2; ++kc)
                bfr[ns][kc] = *(const bf16x8*)
                    &bs[((wc << 6) + (ns << 4) + lrow) * 64 + ((((kc << 2) + quad) ^ sl) << 3)];

        #pragma unroll
        for (int p = 0; p < 4; ++p) {
            bf16x8 af[2][2];
            #pragma unroll
            for (int m = 0; m < 2; ++m)
                #pragma unroll
                for (int kc = 0; kc < 2; ++kc)
                    af[m][kc] = *(const bf16x8*)
                        &as[((wr << 7) + ((p * 2 + m) << 4) + lrow) * 64 + ((((kc << 2) + quad) ^ sl) << 3)];
            __builtin_amdgcn_s_setprio(1);
            #pragma unroll
            for (int kc = 0; kc < 2; ++kc)
                #pragma unroll
                for (int m = 0; m < 2; ++m)
                    #pragma unroll
                    for (int ns = 0; ns < 4; ++ns)
                        acc[p * 2 + m][ns] = __builtin_amdgcn_mfma_f32_16x16x32_bf16(
                            af[m][kc], bfr[ns][kc], acc[p * 2 + m][ns], 0, 0, 0);
            __builtin_amdgcn_s_setprio(0);
        }

        asm volatile("s_waitcnt lgkmcnt(0)" ::: "memory");
        asm volatile("s_waitcnt vmcnt(0)" ::: "memory");
        __builtin_amdgcn_s_barrier();
        __builtin_amdgcn_sched_barrier(0);
        cur ^= 1;
    }

    #pragma unroll
    for (int ms = 0; ms < 8; ++ms) {
        #pragma unroll
        for (int ns = 0; ns < 4; ++ns) {
            const long col = colbase + (wc << 6) + (ns << 4) + lrow;
            float bv;
            if constexpr (MODE == 0) {
                const int which = (int)(col >> 10);
                const float* bp = which == 0 ? bias0 : (which == 1 ? bias1 : bias2);
                bv = bp[col & 1023];
            } else {
                bv = bias0[col];
            }
            #pragma unroll
            for (int r = 0; r < 4; ++r) {
                const long row = rowbase + (wr << 7) + (ms << 4) + (quad << 2) + r;
                float v = acc[ms][ns][r] + bv;
                if constexpr (MODE == 0) {
                    const long which = col >> 10;
                    if (which == 0) v *= 0.18033688f;   // 0.125*log2(e) into Q
                    const long b = row >> 11, s = row & 2047;
                    const long h = (col >> 6) & 15, d = col & 63;
                    ((u16*)outv)[which * 4194304 + (((b << 4) + h) * 2048 + s) * 64 + d] = f2bf(v);
                } else {
                    ((u16*)outv)[row * M + col] = f2bf(gelu_exact(v));
                }
            }
        }
    }
}

// ---------------------------------------------------------------------------
// FF2: 128x128-tile split-K=2, 8 waves x (64x32 output) = 512 threads.
// z=0 -> out (+bias+res folded), z=1 -> part1; add_kernel combines.
// ---------------------------------------------------------------------------
__global__ __launch_bounds__(512, 2) void gemm_ff2_kernel(
    const u16* __restrict__ A, const u16* __restrict__ Bt,
    const float* __restrict__ bias0, const float* __restrict__ res,
    float* __restrict__ part1, float* __restrict__ out, int K, int M)
{
    __shared__ u16 As[2][128 * 64];   // 16 KB each
    __shared__ u16 Bs[2][128 * 64];   // 16 KB each
    const int tid = threadIdx.x, lane = tid & 63, wave = tid >> 6;
    const int wr = wave >> 2, wc = wave & 3;
    const int lrow = lane & 15, quad = lane >> 4, sl = lrow & 7;

    const int nwg = gridDim.x * gridDim.y * gridDim.z;
    const int lin = blockIdx.x + gridDim.x * (blockIdx.y + gridDim.y * blockIdx.z);
    const int wg  = (lin & 7) * (nwg >> 3) + (lin >> 3);
    const int bx  = wg % gridDim.x;
    const int rest = wg / gridDim.x;
    const int by  = rest % gridDim.y;
    const int bz  = rest / gridDim.y;

    const long rowbase = (long)by * 128;
    const long colbase = (long)bx * 128;
    const int kstart = bz * (K >> 1);
    const int kend   = kstart + (K >> 1);

    const u16* gA[2]; int lA[2];
    const u16* gB[2]; int lB[2];
    #pragma unroll
    for (int i = 0; i < 2; ++i) {
        const int cid = (i << 9) + tid;
        const int rl = cid >> 3, p = cid & 7, q = p ^ (rl & 7);
        gA[i] = A  + (rowbase + rl) * (long)K + kstart + (q << 3);
        gB[i] = Bt + (colbase + rl) * (long)K + kstart + (q << 3);
        lA[i] = rl * 64 + (p << 3);
        lB[i] = rl * 64 + (p << 3);
    }

    floatx4 acc[4][2];
    #pragma unroll
    for (int i = 0; i < 4; ++i)
        #pragma unroll
        for (int j = 0; j < 2; ++j)
            acc[i][j] = floatx4{0.f, 0.f, 0.f, 0.f};

    #pragma unroll
    for (int i = 0; i < 2; ++i) { gld_lds16(gA[i], As[0] + lA[i]); gA[i] += 64; }
    #pragma unroll
    for (int i = 0; i < 2; ++i) { gld_lds16(gB[i], Bs[0] + lB[i]); gB[i] += 64; }
    asm volatile("s_waitcnt vmcnt(0)" ::: "memory");
    __builtin_amdgcn_s_barrier();
    __builtin_amdgcn_sched_barrier(0);

    const int niter = (kend - kstart) >> 6;
    int cur = 0;
    for (int t = 0; t < niter; ++t) {
        if (t + 1 < niter) {
            #pragma unroll
            for (int i = 0; i < 2; ++i) { gld_lds16(gA[i], As[cur ^ 1] + lA[i]); gA[i] += 64; }
            #pragma unroll
            for (int i = 0; i < 2; ++i) { gld_lds16(gB[i], Bs[cur ^ 1] + lB[i]); gB[i] += 64; }
        }

        const u16* as = As[cur];
        const u16* bs = Bs[cur];

        bf16x8 bfr[2][2], af[4][2];
        #pragma unroll
        for (int ns = 0; ns < 2; ++ns)
            #pragma unroll
            for (int kc = 0; kc < 2; ++kc)
                bfr[ns][kc] = *(const bf16x8*)
                    &bs[((wc << 5) + (ns << 4) + lrow) * 64 + ((((kc << 2) + quad) ^ sl) << 3)];
        #pragma unroll
        for (int m = 0; m < 4; ++m)
            #pragma unroll
            for (int kc = 0; kc < 2; ++kc)
                af[m][kc] = *(const bf16x8*)
                    &as[((wr << 6) + (m << 4) + lrow) * 64 + ((((kc << 2) + quad) ^ sl) << 3)];

        __builtin_amdgcn_s_setprio(1);
        #pragma unroll
        for (int kc = 0; kc < 2; ++kc)
            #pragma unroll
            for (int m = 0; m < 4; ++m)
                #pragma unroll
                for (int ns = 0; ns < 2; ++ns)
                    acc[m][ns] = __builtin_amdgcn_mfma_f32_16x16x32_bf16(
                        af[m][kc], bfr[ns][kc], acc[m][ns], 0, 0, 0);
        __builtin_amdgcn_s_setprio(0);

        asm volatile("s_waitcnt lgkmcnt(0)" ::: "memory");
        asm volatile("s_waitcnt vmcnt(0)" ::: "memory");
        __builtin_amdgcn_s_barrier();
        __builtin_amdgcn_sched_barrier(0);
        cur ^= 1;
    }

    float* tgt = bz ? part1 : out;
    #pragma unroll
    for (int m = 0; m < 4; ++m) {
        #pragma unroll
        for (int ns = 0; ns < 2; ++ns) {
            const long col = colbase + (wc << 5) + (ns << 4) + lrow;
            #pragma unroll
            for (int r = 0; r < 4; ++r) {
                const long row = rowbase + (wr << 6) + (m << 4) + (quad << 2) + r;
                const long idx = row * M + col;
                float v = acc[m][ns][r];
                if (bz == 0)
                    tgt[idx] = v + bias0[col] + res[idx];  // fold b2 + residual
                else
                    tgt[idx] = v;
            }
        }
    }
}

// ---------------------------------------------------------------------------
// 128x64 GEMM (O-proj): single-buffer 2-phase, 24 KB LDS -> high TLP.
// out fp32 row-major, +bias +res.
// ---------------------------------------------------------------------------
__global__ __launch_bounds__(256) void gemm_oproj_kernel(
    const u16* __restrict__ A, const u16* __restrict__ Bt,
    const float* __restrict__ bias0, const float* __restrict__ res,
    float* __restrict__ out, int K, int M)
{
    constexpr int MS = 2, NIB = 2;
    __shared__ u16 As[128 * 64];
    __shared__ u16 Bs[64 * 64];
    const int tid = threadIdx.x, lane = tid & 63, wave = tid >> 6;
    const int wm = wave << 5, wn = 0;
    const int lrow = lane & 15, quad = lane >> 4;
    const int sl = lrow & 7;

    const int nwg = gridDim.x * gridDim.y;
    const int lin = blockIdx.x + gridDim.x * blockIdx.y;
    const int wg  = (lin & 7) * (nwg >> 3) + (lin >> 3);
    const int bx  = wg % gridDim.x;
    const int by  = wg / gridDim.x;

    const long rowbase = (long)by * 128;
    const long colbase = (long)bx * 64;

    const u16* gA[4]; int lA[4];
    #pragma unroll
    for (int i = 0; i < 4; ++i) {
        const int cid = (i << 6) + lane;
        const int rl = cid >> 3, p = cid & 7, q = p ^ (rl & 7);
        gA[i] = A + (rowbase + (wave << 5) + rl) * (long)K + (q << 3);
        lA[i] = ((wave << 5) + rl) * 64 + (p << 3);
    }
    const u16* gB[NIB]; int lB[NIB];
    #pragma unroll
    for (int i = 0; i < NIB; ++i) {
        const int cid = (i << 6) + lane;
        const int rl = cid >> 3, p = cid & 7, q = p ^ (rl & 7);
        gB[i] = Bt + (colbase + (wave << 4) + rl) * (long)K + (q << 3);
        lB[i] = ((wave << 4) + rl) * 64 + (p << 3);
    }

    floatx4 acc[MS][4];
    #pragma unroll
    for (int i = 0; i < MS; ++i)
        #pragma unroll
        for (int j = 0; j < 4; ++j)
            acc[i][j] = floatx4{0.f, 0.f, 0.f, 0.f};

    for (int k0 = 0; k0 < K; k0 += 64) {
        __syncthreads();
        #pragma unroll
        for (int i = 0; i < 4; ++i) { gld_lds16(gA[i], As + lA[i]); gA[i] += 64; }
        #pragma unroll
        for (int i = 0; i < NIB; ++i) { gld_lds16(gB[i], Bs + lB[i]); gB[i] += 64; }
        __syncthreads();
        #pragma unroll
        for (int kc = 0; kc < 2; ++kc) {
            const int ph = (((kc << 2) + quad) ^ sl) << 3;
            bf16x8 af[MS], bf[4];
            #pragma unroll
            for (int ms = 0; ms < MS; ++ms)
                af[ms] = *(const bf16x8*)&As[(wm + (ms << 4) + lrow) * 64 + ph];
            #pragma unroll
            for (int ns = 0; ns < 4; ++ns)
                bf[ns] = *(const bf16x8*)&Bs[(wn + (ns << 4) + lrow) * 64 + ph];
            #pragma unroll
            for (int ms = 0; ms < MS; ++ms)
                #pragma unroll
                for (int ns = 0; ns < 4; ++ns)
                    acc[ms][ns] = __builtin_amdgcn_mfma_f32_16x16x32_bf16(
                        af[ms], bf[ns], acc[ms][ns], 0, 0, 0);
        }
    }

    #pragma unroll
    for (int ms = 0; ms < MS; ++ms) {
        #pragma unroll
        for (int ns = 0; ns < 4; ++ns) {
            const long col = colbase + wn + (ns << 4) + lrow;
            const float bv = bias0[col];
            #pragma unroll
            for (int r = 0; r < 4; ++r) {
                const long row = rowbase + wm + (ms << 4) + (quad << 2) + r;
                const long idx = row * M + col;
                out[idx] = acc[ms][ns][r] + bv + res[idx];
            }
        }
    }
}

// ---------------------------------------------------------------------------
// Flash attention v11 = r9's v9 (best measured: 55.4us) + cvt_pk softmax
// pack: v_cvt_pk_bf16_f32 (2 insts) replaces 4 bias-adds + 2 v_perm per ns.
// VALU was the busier pipe (41% vs MfmaUtil 25%) - this trims ~15% of the
// softmax VALU. Split-KV (r10) REVERTED: VGPR 40->84, occupancy 34->20.
// ---------------------------------------------------------------------------
__global__ __launch_bounds__(512) void attn_kernel(
    const u16* __restrict__ Q, const u16* __restrict__ Kp,
    const u16* __restrict__ Vt, u16* __restrict__ O)
{
    __shared__ u16 Ks[2][4096];       // 16 KB (dbuf)
    __shared__ u16 Vs[2][4096];       // 16 KB (dbuf)
    __shared__ u16 Ps[8][16][72];     // 18 KB
    const int tid = threadIdx.x, lane = tid & 63, wave = tid >> 6;
    const int lrow = lane & 15, quad = lane >> 4;

    // XCD-bijective swizzle: lin -> (xcd chunk of 64) -> 4 heads per XCD.
    const int lin = blockIdx.x;
    const int nl  = ((lin & 7) << 6) + (lin >> 3);
    const int bh  = nl >> 4;
    const int qt  = nl & 15;
    const long kvbase = (long)bh * 2048 * 64;
    const int qbase = (qt << 7) + (wave << 4);

    // Staging: wave role split. c = quarter index (16 rows of the 64-row tile).
    const int srow = lane >> 3;
    const int schunk = (lane & 7) ^ srow;
    const int c = wave & 3;
    const bool isV = wave >= 4;
    const int lofs = c << 10;
    const u16* g0 = isV
        ? (Vt + kvbase + (long)(((c << 4) + srow) * 2048 + (schunk << 3)))
        : (Kp + kvbase + (long)(((c << 4) + srow) * 64   + (schunk << 3)));
    const u16* g1 = g0 + (isV ? 8 * 2048 : 8 * 64);
    const int gstep = isV ? 64 : 4096;
    u16* lb0 = isV ? &Vs[0][lofs] : &Ks[0][lofs];
    u16* lb1 = isV ? &Vs[1][lofs] : &Ks[1][lofs];

    bf16x8 qf[2];
    #pragma unroll
    for (int h = 0; h < 2; ++h)
        qf[h] = *(const bf16x8*)(Q + kvbase +
            (long)(qbase + lrow) * 64 + (quad << 3) + (h << 5));

    int aoff[4][2];
    #pragma unroll
    for (int ns = 0; ns < 4; ++ns)
        #pragma unroll
        for (int h = 0; h < 2; ++h)
            aoff[ns][h] = ((ns << 4) + lrow) * 64 +
                          (((quad + (h << 2)) ^ (lrow & 7)) << 3);

    floatx4 oacc[4];
    #pragma unroll
    for (int ns = 0; ns < 4; ++ns)
        oacc[ns] = floatx4{0.f, 0.f, 0.f, 0.f};
    float lr = 0.f;

    gld_lds16(g0, lb0);
    gld_lds16(g1, lb0 + 512);
    g0 += gstep; g1 += gstep;

    for (int it = 0; it < 32; ++it) {
        const int cur = it & 1;
        __syncthreads();
        if (it < 31) {
            u16* dst = cur ? lb0 : lb1;
            gld_lds16(g0, dst);
            gld_lds16(g1, dst + 512);
            g0 += gstep; g1 += gstep;
        }
        const u16* ks = &Ks[cur][0];
        const u16* vs = &Vs[cur][0];

        floatx4 st[4];
        __builtin_amdgcn_s_setprio(1);
        #pragma unroll
        for (int ns = 0; ns < 4; ++ns) {
            const bf16x8 af0 = *(const bf16x8*)&ks[aoff[ns][0]];
            const bf16x8 af1 = *(const bf16x8*)&ks[aoff[ns][1]];
            floatx4 z = floatx4{0.f, 0.f, 0.f, 0.f};
            st[ns] = __builtin_amdgcn_mfma_f32_16x16x32_bf16(af0, qf[0], z, 0, 0, 0);
            st[ns] = __builtin_amdgcn_mfma_f32_16x16x32_bf16(af1, qf[1], st[ns], 0, 0, 0);
        }
        __builtin_amdgcn_s_setprio(0);

        float rs = 0.f;
        #pragma unroll
        for (int ns = 0; ns < 4; ++ns) {
            const float p0 = __builtin_amdgcn_exp2f(st[ns][0]);
            const float p1 = __builtin_amdgcn_exp2f(st[ns][1]);
            const float p2 = __builtin_amdgcn_exp2f(st[ns][2]);
            const float p3 = __builtin_amdgcn_exp2f(st[ns][3]);
            rs += (p0 + p1) + (p2 + p3);
            uint2 w;
            asm("v_cvt_pk_bf16_f32 %0, %1, %2" : "=v"(w.x) : "v"(p0), "v"(p1));
            asm("v_cvt_pk_bf16_f32 %0, %1, %2" : "=v"(w.y) : "v"(p2), "v"(p3));
            *(uint2*)&Ps[wave][lrow][(ns << 4) + (quad << 2)] = w;
        }
        rs += __shfl_xor(rs, 16);
        rs += __shfl_xor(rs, 32);
        lr += rs;
        const bf16x8 pf0 = *(const bf16x8*)&Ps[wave][lrow][quad << 3];
        const bf16x8 pf1 = *(const bf16x8*)&Ps[wave][lrow][(quad << 3) + 32];

        __builtin_amdgcn_s_setprio(1);
        #pragma unroll
        for (int ns = 0; ns < 4; ++ns) {
            const bf16x8 vf0 = *(const bf16x8*)&vs[aoff[ns][0]];
            const bf16x8 vf1 = *(const bf16x8*)&vs[aoff[ns][1]];
            oacc[ns] = __builtin_amdgcn_mfma_f32_16x16x32_bf16(pf0, vf0, oacc[ns], 0, 0, 0);
            oacc[ns] = __builtin_amdgcn_mfma_f32_16x16x32_bf16(pf1, vf1, oacc[ns], 0, 0, 0);
        }
        __builtin_amdgcn_s_setprio(0);
    }

    const int b = bh >> 4, h = bh & 15;
    float linv[4];
    #pragma unroll
    for (int r = 0; r < 4; ++r)
        linv[r] = 1.0f / __shfl(lr, (quad << 2) + r);
    #pragma unroll
    for (int ns = 0; ns < 4; ++ns)
        #pragma unroll
        for (int r = 0; r < 4; ++r) {
            const int q = qbase + (quad << 2) + r;
            const long token = (long)b * 2048 + q;
            O[token * 1024 + (h << 6) + (ns << 4) + lrow] =
                f2bf(oacc[ns][r] * linv[r]);
        }
}

// ---------------------------------------------------------------------------
// Host launcher
// ---------------------------------------------------------------------------
extern "C" void kernel_launch(void* const* d_in, const int* in_sizes, int n_in,
                              void* d_out, int out_size, void* d_ws, size_t ws_size,
                              hipStream_t stream)
{
    const float* x     = (const float*)d_in[0];
    const float* ln1_g = (const float*)d_in[1];
    const float* ln1_b = (const float*)d_in[2];
    const float* wq    = (const float*)d_in[3];
    const float* bq    = (const float*)d_in[4];
    const float* wk    = (const float*)d_in[5];
    const float* bk    = (const float*)d_in[6];
    const float* wv    = (const float*)d_in[7];
    const float* bv    = (const float*)d_in[8];
    const float* wo    = (const float*)d_in[9];
    const float* bo    = (const float*)d_in[10];
    const float* w1    = (const float*)d_in[11];
    const float* b1    = (const float*)d_in[12];
    const float* w2    = (const float*)d_in[13];
    const float* b2    = (const float*)d_in[14];
    const float* ln2_g = (const float*)d_in[15];
    const float* ln2_b = (const float*)d_in[16];
    float* out = (float*)d_out;

    char* w = (char*)d_ws;
    const size_t MB = 1024 * 1024;
    u16*   wqkvt = (u16*)(w + 0);        // [0,6) MB
    u16*   wot   = (u16*)(w + 6  * MB);  // [6,8)
    u16*   w1t   = (u16*)(w + 8  * MB);  // [8,16)
    u16*   w2t   = (u16*)(w + 16 * MB);  // [16,24)
    u16*   h1    = (u16*)(w + 24 * MB);  // [24,32): ln1 / attn-out / ln2
    u16*   qkvb  = (u16*)(w + 32 * MB);  // [32,56): Q|K|V (bh,s,d)
    u16*   vtb   = (u16*)(w + 56 * MB);  // [56,64): V^T (bh,d,s)
    float* x1    = (float*)(w + 64 * MB);// [64,80): fp32 residual-1
    float* part1 = (float*)(w + 80 * MB);// [80,96): FF2 split-K partial z=1
    u16*   ffb   = (u16*)(w + 32 * MB);  // [32,64): FF hidden (reuses qkv/vtb)
    u16*   qb = qkvb;
    u16*   kb = qkvb + 4194304;
    u16*   vb = qkvb + 8388608;

    transpose_cvt4<<<dim3(32, 32, 4), 256, 0, stream>>>(
        wq, wk, wv, wo, wqkvt, wqkvt + 1048576, wqkvt + 2097152, wot);
    transpose_cvt<<<dim3(128, 32), 256, 0, stream>>>(w1, w1t, 1024, 4096);
    transpose_cvt<<<dim3(32, 128), 256, 0, stream>>>(w2, w2t, 4096, 1024);

    ln_kernel<<<4096, 256, 0, stream>>>(x, ln1_g, ln1_b, h1);

    // QKV: 4096x3072, K=1024. 256^2 tiles -> 192 blocks.
    gemm256_kernel<0><<<dim3(12, 16), 512, 0, stream>>>(
        h1, wqkvt, bq, bk, bv, qkvb, 1024, 3072);

    vtrans_kernel<<<dim3(32, 32), 256, 0, stream>>>(vb, vtb);

    attn_kernel<<<dim3(512), 512, 0, stream>>>(qb, kb, vtb, h1);

    // O-proj: 4096x1024, K=1024. 128x64 single-buffer, high TLP.
    gemm_oproj_kernel<<<dim3(16, 32), 256, 0, stream>>>(
        h1, wot, bo, x, x1, 1024, 1024);

    ln_kernel<<<4096, 256, 0, stream>>>(x1, ln2_g, ln2_b, h1);

    // FF1: 4096x4096, K=1024. 256^2 tiles -> 256 blocks = 1/CU.
    gemm256_kernel<2><<<dim3(16, 16), 512, 0, stream>>>(
        h1, w1t, b1, nullptr, nullptr, ffb, 1024, 4096);

    // FF2: 4096x1024, K=4096. 128^2 8-wave dbuf split-K=2 -> 512 blocks.
    gemm_ff2_kernel<<<dim3(8, 32, 2), 512, 0, stream>>>(
        ffb, w2t, b2, x1, part1, out, 4096, 1024);

    add_kernel<<<4096, 256, 0, stream>>>(out, part1);
}

// Round 12
// 344.576 us; speedup vs baseline: 1.0766x; 1.0084x over previous
//
#include <hip/hip_runtime.h>

typedef unsigned short u16;
typedef unsigned int u32;
typedef __bf16 bf16x8 __attribute__((ext_vector_type(8)));
typedef float floatx4 __attribute__((ext_vector_type(4)));

__device__ __forceinline__ u16 f2bf(float f) {
    u32 u = __float_as_uint(f);
    u = (u + 0x7FFFu + ((u >> 16) & 1u)) >> 16;
    return (u16)u;
}

__device__ __forceinline__ void gld_lds16(const u16* g, u16* l) {
    __builtin_amdgcn_global_load_lds(
        (const __attribute__((address_space(1))) u32*)g,
        (__attribute__((address_space(3))) u32*)l, 16, 0, 0);
}

// Exact-enough GELU: erf via Abramowitz-Stegun 7.1.26 (|err| < 1.5e-7).
__device__ __forceinline__ float gelu_exact(float v) {
    const float z = fabsf(v) * 0.70710678118f;
    const float t = __builtin_amdgcn_rcpf(1.0f + 0.3275911f * z);
    const float e = __builtin_amdgcn_exp2f(-z * z * 1.44269504f);
    float poly = 1.061405429f;
    poly = poly * t - 1.453152027f;
    poly = poly * t + 1.421413741f;
    poly = poly * t - 0.284496736f;
    poly = poly * t + 0.254829592f;
    float erfz = 1.0f - poly * t * e;
    erfz = copysignf(erfz, v);
    return 0.5f * v * (1.0f + erfz);
}

// ---------------------------------------------------------------------------
// Four 1024x1024 transposes + fp32->bf16 in one launch (z picks the matrix).
// ---------------------------------------------------------------------------
__global__ __launch_bounds__(256) void transpose_cvt4(
    const float* __restrict__ s0, const float* __restrict__ s1,
    const float* __restrict__ s2, const float* __restrict__ s3,
    u16* __restrict__ d0, u16* __restrict__ d1,
    u16* __restrict__ d2, u16* __restrict__ d3)
{
    __shared__ float t[32][33];
    const int z = blockIdx.z;
    const float* src = z == 0 ? s0 : (z == 1 ? s1 : (z == 2 ? s2 : s3));
    u16* dst = z == 0 ? d0 : (z == 1 ? d1 : (z == 2 ? d2 : d3));
    const int bm = blockIdx.x * 32, bk = blockIdx.y * 32;
    const int tx = threadIdx.x & 31, ty = threadIdx.x >> 5;
    #pragma unroll
    for (int i = ty; i < 32; i += 8)
        t[i][tx] = src[(long)(bk + i) * 1024 + bm + tx];
    __syncthreads();
    #pragma unroll
    for (int i = ty; i < 32; i += 8)
        dst[(long)(bm + i) * 1024 + bk + tx] = f2bf(t[tx][i]);
}

// ---------------------------------------------------------------------------
// Transpose + fp32->bf16: src K x M -> dst M x K.
// ---------------------------------------------------------------------------
__global__ __launch_bounds__(256) void transpose_cvt(
    const float* __restrict__ src, u16* __restrict__ dst, int K, int M)
{
    __shared__ float t[32][33];
    const int bm = blockIdx.x * 32, bk = blockIdx.y * 32;
    const int tx = threadIdx.x & 31, ty = threadIdx.x >> 5;
    #pragma unroll
    for (int i = ty; i < 32; i += 8)
        t[i][tx] = src[(long)(bk + i) * M + bm + tx];
    __syncthreads();
    #pragma unroll
    for (int i = ty; i < 32; i += 8)
        dst[(long)(bm + i) * K + bk + tx] = f2bf(t[tx][i]);
}

// ---------------------------------------------------------------------------
// LayerNorm over rows of 1024 fp32 -> bf16. One block per row.
// ---------------------------------------------------------------------------
__global__ __launch_bounds__(256) void ln_kernel(
    const float* __restrict__ x, const float* __restrict__ g,
    const float* __restrict__ bta, u16* __restrict__ out)
{
    const int row = blockIdx.x;
    const int tid = threadIdx.x;
    const float4 v = ((const float4*)(x + (long)row * 1024))[tid];
    float s  = v.x + v.y + v.z + v.w;
    float s2 = v.x*v.x + v.y*v.y + v.z*v.z + v.w*v.w;
    #pragma unroll
    for (int off = 1; off < 64; off <<= 1) {
        s  += __shfl_xor(s, off);
        s2 += __shfl_xor(s2, off);
    }
    __shared__ float red[8];
    const int wave = tid >> 6, lane = tid & 63;
    if (lane == 0) { red[wave] = s; red[4 + wave] = s2; }
    __syncthreads();
    s  = red[0] + red[1] + red[2] + red[3];
    s2 = red[4] + red[5] + red[6] + red[7];
    const float mu   = s * (1.0f / 1024.0f);
    const float var  = s2 * (1.0f / 1024.0f) - mu * mu;
    const float rstd = rsqrtf(var + 1e-5f);
    const int c = tid << 2;
    ushort4 o;
    o.x = f2bf((v.x - mu) * rstd * g[c + 0] + bta[c + 0]);
    o.y = f2bf((v.y - mu) * rstd * g[c + 1] + bta[c + 1]);
    o.z = f2bf((v.z - mu) * rstd * g[c + 2] + bta[c + 2]);
    o.w = f2bf((v.w - mu) * rstd * g[c + 3] + bta[c + 3]);
    ((ushort4*)(out + (long)row * 1024))[tid] = o;
}

// ---------------------------------------------------------------------------
// Split-K combine: out[i] += p1[i].
// ---------------------------------------------------------------------------
__global__ __launch_bounds__(256) void add_kernel(
    float* __restrict__ out, const float* __restrict__ p1)
{
    const int t = blockIdx.x * 256 + threadIdx.x;
    const float4 a = ((const float4*)out)[t];
    const float4 c = ((const float4*)p1)[t];
    float4 o;
    o.x = a.x + c.x;
    o.y = a.y + c.y;
    o.z = a.z + c.z;
    o.w = a.w + c.w;
    ((float4*)out)[t] = o;
}

// ---------------------------------------------------------------------------
// V transpose per (b,h): (bh, s=2048, d=64) -> (bh, d=64, s=2048), bf16.
// ---------------------------------------------------------------------------
__global__ __launch_bounds__(256) void vtrans_kernel(
    const u16* __restrict__ V, u16* __restrict__ Vt)
{
    __shared__ u16 t[64][72];
    const int bh = blockIdx.y, s0 = blockIdx.x << 6;
    const int tid = threadIdx.x;
    const long base = (long)bh * 2048 * 64;
    const int row = tid >> 2, seg = tid & 3;
    *(uint4*)&t[row][seg << 3] =
        *(const uint4*)(V + base + (long)(s0 + row) * 64 + (seg << 3));
    *(uint4*)&t[row][(seg + 4) << 3] =
        *(const uint4*)(V + base + (long)(s0 + row) * 64 + ((seg + 4) << 3));
    __syncthreads();
    #pragma unroll
    for (int half = 0; half < 2; ++half) {
        const int sl = (seg + (half << 2)) << 3;
        u16 tmp[8];
        #pragma unroll
        for (int j = 0; j < 8; ++j) tmp[j] = t[sl + j][row];
        *(uint4*)(Vt + base + (long)row * 2048 + s0 + sl) = *(uint4*)tmp;
    }
}

// ---------------------------------------------------------------------------
// 256x256-tile GEMM, BK=64, 8 waves (512 thr), dbuf LDS (128 KB, 1 blk/CU),
// early-issue staging, setprio around MFMA clusters.
// MODE 0: out bf16, fused QKV scatter; Q pre-scaled by 0.125*log2(e)
// MODE 2: out bf16 row-major, gelu(v+bias)
// ---------------------------------------------------------------------------
template<int MODE>
__global__ __launch_bounds__(512, 2) void gemm256_kernel(
    const u16* __restrict__ A, const u16* __restrict__ Bt,
    const float* __restrict__ bias0, const float* __restrict__ bias1,
    const float* __restrict__ bias2, void* __restrict__ outv, int K, int M)
{
    __shared__ u16 As[2][256 * 64];   // 32 KB each
    __shared__ u16 Bs[2][256 * 64];   // 32 KB each
    const int tid = threadIdx.x, lane = tid & 63, wave = tid >> 6;
    const int wr = wave >> 2, wc = wave & 3;
    const int lrow = lane & 15, quad = lane >> 4, sl = lrow & 7;

    const int nwg = gridDim.x * gridDim.y;
    const int lin = blockIdx.x + gridDim.x * blockIdx.y;
    const int wg  = (lin & 7) * (nwg >> 3) + (lin >> 3);
    const int bx  = wg % gridDim.x;
    const int by  = wg / gridDim.x;

    const long rowbase = (long)by * 256;
    const long colbase = (long)bx * 256;

    const u16* gA[4]; int lA[4];
    const u16* gB[4]; int lB[4];
    #pragma unroll
    for (int i = 0; i < 4; ++i) {
        const int cid = (i << 9) + tid;
        const int rl = cid >> 3, p = cid & 7, q = p ^ (rl & 7);
        gA[i] = A  + (rowbase + rl) * (long)K + (q << 3);
        gB[i] = Bt + (colbase + rl) * (long)K + (q << 3);
        lA[i] = rl * 64 + (p << 3);
        lB[i] = rl * 64 + (p << 3);
    }

    floatx4 acc[8][4];
    #pragma unroll
    for (int i = 0; i < 8; ++i)
        #pragma unroll
        for (int j = 0; j < 4; ++j)
            acc[i][j] = floatx4{0.f, 0.f, 0.f, 0.f};

    #pragma unroll
    for (int i = 0; i < 4; ++i) { gld_lds16(gA[i], As[0] + lA[i]); gA[i] += 64; }
    #pragma unroll
    for (int i = 0; i < 4; ++i) { gld_lds16(gB[i], Bs[0] + lB[i]); gB[i] += 64; }
    asm volatile("s_waitcnt vmcnt(0)" ::: "memory");
    __builtin_amdgcn_s_barrier();
    __builtin_amdgcn_sched_barrier(0);

    const int niter = K >> 6;
    int cur = 0;
    for (int t = 0; t < niter; ++t) {
        if (t + 1 < niter) {
            #pragma unroll
            for (int i = 0; i < 4; ++i) { gld_lds16(gA[i], As[cur ^ 1] + lA[i]); gA[i] += 64; }
            #pragma unroll
            for (int i = 0; i < 4; ++i) { gld_lds16(gB[i], Bs[cur ^ 1] + lB[i]); gB[i] += 64; }
        }

        const u16* as = As[cur];
        const u16* bs = Bs[cur];

        bf16x8 bfr[4][2];
        #pragma unroll
        for (int ns = 0; ns < 4; ++ns)
            #pragma unroll
            for (int kc = 0; kc < 2; ++kc)
                bfr[ns][kc] = *(const bf16x8*)
                    &bs[((wc << 6) + (ns << 4) + lrow) * 64 + ((((kc << 2) + quad) ^ sl) << 3)];

        #pragma unroll
        for (int p = 0; p < 4; ++p) {
            bf16x8 af[2][2];
            #pragma unroll
            for (int m = 0; m < 2; ++m)
                #pragma unroll
                for (int kc = 0; kc < 2; ++kc)
                    af[m][kc] = *(const bf16x8*)
                        &as[((wr << 7) + ((p * 2 + m) << 4) + lrow) * 64 + ((((kc << 2) + quad) ^ sl) << 3)];
            __builtin_amdgcn_s_setprio(1);
            #pragma unroll
            for (int kc = 0; kc < 2; ++kc)
                #pragma unroll
                for (int m = 0; m < 2; ++m)
                    #pragma unroll
                    for (int ns = 0; ns < 4; ++ns)
                        acc[p * 2 + m][ns] = __builtin_amdgcn_mfma_f32_16x16x32_bf16(
                            af[m][kc], bfr[ns][kc], acc[p * 2 + m][ns], 0, 0, 0);
            __builtin_amdgcn_s_setprio(0);
        }

        asm volatile("s_waitcnt lgkmcnt(0)" ::: "memory");
        asm volatile("s_waitcnt vmcnt(0)" ::: "memory");
        __builtin_amdgcn_s_barrier();
        __builtin_amdgcn_sched_barrier(0);
        cur ^= 1;
    }

    #pragma unroll
    for (int ms = 0; ms < 8; ++ms) {
        #pragma unroll
        for (int ns = 0; ns < 4; ++ns) {
            const long col = colbase + (wc << 6) + (ns << 4) + lrow;
            float bv;
            if constexpr (MODE == 0) {
                const int which = (int)(col >> 10);
                const float* bp = which == 0 ? bias0 : (which == 1 ? bias1 : bias2);
                bv = bp[col & 1023];
            } else {
                bv = bias0[col];
            }
            #pragma unroll
            for (int r = 0; r < 4; ++r) {
                const long row = rowbase + (wr << 7) + (ms << 4) + (quad << 2) + r;
                float v = acc[ms][ns][r] + bv;
                if constexpr (MODE == 0) {
                    const long which = col >> 10;
                    if (which == 0) v *= 0.18033688f;   // 0.125*log2(e) into Q
                    const long b = row >> 11, s = row & 2047;
                    const long h = (col >> 6) & 15, d = col & 63;
                    ((u16*)outv)[which * 4194304 + (((b << 4) + h) * 2048 + s) * 64 + d] = f2bf(v);
                } else {
                    ((u16*)outv)[row * M + col] = f2bf(gelu_exact(v));
                }
            }
        }
    }
}

// ---------------------------------------------------------------------------
// FF2: 128x128-tile split-K=2, 8 waves x (64x32 output) = 512 threads.
// z=0 -> out (+bias+res folded), z=1 -> part1; add_kernel combines.
// ---------------------------------------------------------------------------
__global__ __launch_bounds__(512, 2) void gemm_ff2_kernel(
    const u16* __restrict__ A, const u16* __restrict__ Bt,
    const float* __restrict__ bias0, const float* __restrict__ res,
    float* __restrict__ part1, float* __restrict__ out, int K, int M)
{
    __shared__ u16 As[2][128 * 64];   // 16 KB each
    __shared__ u16 Bs[2][128 * 64];   // 16 KB each
    const int tid = threadIdx.x, lane = tid & 63, wave = tid >> 6;
    const int wr = wave >> 2, wc = wave & 3;
    const int lrow = lane & 15, quad = lane >> 4, sl = lrow & 7;

    const int nwg = gridDim.x * gridDim.y * gridDim.z;
    const int lin = blockIdx.x + gridDim.x * (blockIdx.y + gridDim.y * blockIdx.z);
    const int wg  = (lin & 7) * (nwg >> 3) + (lin >> 3);
    const int bx  = wg % gridDim.x;
    const int rest = wg / gridDim.x;
    const int by  = rest % gridDim.y;
    const int bz  = rest / gridDim.y;

    const long rowbase = (long)by * 128;
    const long colbase = (long)bx * 128;
    const int kstart = bz * (K >> 1);
    const int kend   = kstart + (K >> 1);

    const u16* gA[2]; int lA[2];
    const u16* gB[2]; int lB[2];
    #pragma unroll
    for (int i = 0; i < 2; ++i) {
        const int cid = (i << 9) + tid;
        const int rl = cid >> 3, p = cid & 7, q = p ^ (rl & 7);
        gA[i] = A  + (rowbase + rl) * (long)K + kstart + (q << 3);
        gB[i] = Bt + (colbase + rl) * (long)K + kstart + (q << 3);
        lA[i] = rl * 64 + (p << 3);
        lB[i] = rl * 64 + (p << 3);
    }

    floatx4 acc[4][2];
    #pragma unroll
    for (int i = 0; i < 4; ++i)
        #pragma unroll
        for (int j = 0; j < 2; ++j)
            acc[i][j] = floatx4{0.f, 0.f, 0.f, 0.f};

    #pragma unroll
    for (int i = 0; i < 2; ++i) { gld_lds16(gA[i], As[0] + lA[i]); gA[i] += 64; }
    #pragma unroll
    for (int i = 0; i < 2; ++i) { gld_lds16(gB[i], Bs[0] + lB[i]); gB[i] += 64; }
    asm volatile("s_waitcnt vmcnt(0)" ::: "memory");
    __builtin_amdgcn_s_barrier();
    __builtin_amdgcn_sched_barrier(0);

    const int niter = (kend - kstart) >> 6;
    int cur = 0;
    for (int t = 0; t < niter; ++t) {
        if (t + 1 < niter) {
            #pragma unroll
            for (int i = 0; i < 2; ++i) { gld_lds16(gA[i], As[cur ^ 1] + lA[i]); gA[i] += 64; }
            #pragma unroll
            for (int i = 0; i < 2; ++i) { gld_lds16(gB[i], Bs[cur ^ 1] + lB[i]); gB[i] += 64; }
        }

        const u16* as = As[cur];
        const u16* bs = Bs[cur];

        bf16x8 bfr[2][2], af[4][2];
        #pragma unroll
        for (int ns = 0; ns < 2; ++ns)
            #pragma unroll
            for (int kc = 0; kc < 2; ++kc)
                bfr[ns][kc] = *(const bf16x8*)
                    &bs[((wc << 5) + (ns << 4) + lrow) * 64 + ((((kc << 2) + quad) ^ sl) << 3)];
        #pragma unroll
        for (int m = 0; m < 4; ++m)
            #pragma unroll
            for (int kc = 0; kc < 2; ++kc)
                af[m][kc] = *(const bf16x8*)
                    &as[((wr << 6) + (m << 4) + lrow) * 64 + ((((kc << 2) + quad) ^ sl) << 3)];

        __builtin_amdgcn_s_setprio(1);
        #pragma unroll
        for (int kc = 0; kc < 2; ++kc)
            #pragma unroll
            for (int m = 0; m < 4; ++m)
                #pragma unroll
                for (int ns = 0; ns < 2; ++ns)
                    acc[m][ns] = __builtin_amdgcn_mfma_f32_16x16x32_bf16(
                        af[m][kc], bfr[ns][kc], acc[m][ns], 0, 0, 0);
        __builtin_amdgcn_s_setprio(0);

        asm volatile("s_waitcnt lgkmcnt(0)" ::: "memory");
        asm volatile("s_waitcnt vmcnt(0)" ::: "memory");
        __builtin_amdgcn_s_barrier();
        __builtin_amdgcn_sched_barrier(0);
        cur ^= 1;
    }

    float* tgt = bz ? part1 : out;
    #pragma unroll
    for (int m = 0; m < 4; ++m) {
        #pragma unroll
        for (int ns = 0; ns < 2; ++ns) {
            const long col = colbase + (wc << 5) + (ns << 4) + lrow;
            #pragma unroll
            for (int r = 0; r < 4; ++r) {
                const long row = rowbase + (wr << 6) + (m << 4) + (quad << 2) + r;
                const long idx = row * M + col;
                float v = acc[m][ns][r];
                if (bz == 0)
                    tgt[idx] = v + bias0[col] + res[idx];  // fold b2 + residual
                else
                    tgt[idx] = v;
            }
        }
    }
}

// ---------------------------------------------------------------------------
// 128x64 GEMM (O-proj): single-buffer 2-phase, 24 KB LDS -> high TLP.
// out fp32 row-major, +bias +res.
// ---------------------------------------------------------------------------
__global__ __launch_bounds__(256) void gemm_oproj_kernel(
    const u16* __restrict__ A, const u16* __restrict__ Bt,
    const float* __restrict__ bias0, const float* __restrict__ res,
    float* __restrict__ out, int K, int M)
{
    constexpr int MS = 2, NIB = 2;
    __shared__ u16 As[128 * 64];
    __shared__ u16 Bs[64 * 64];
    const int tid = threadIdx.x, lane = tid & 63, wave = tid >> 6;
    const int wm = wave << 5, wn = 0;
    const int lrow = lane & 15, quad = lane >> 4;
    const int sl = lrow & 7;

    const int nwg = gridDim.x * gridDim.y;
    const int lin = blockIdx.x + gridDim.x * blockIdx.y;
    const int wg  = (lin & 7) * (nwg >> 3) + (lin >> 3);
    const int bx  = wg % gridDim.x;
    const int by  = wg / gridDim.x;

    const long rowbase = (long)by * 128;
    const long colbase = (long)bx * 64;

    const u16* gA[4]; int lA[4];
    #pragma unroll
    for (int i = 0; i < 4; ++i) {
        const int cid = (i << 6) + lane;
        const int rl = cid >> 3, p = cid & 7, q = p ^ (rl & 7);
        gA[i] = A + (rowbase + (wave << 5) + rl) * (long)K + (q << 3);
        lA[i] = ((wave << 5) + rl) * 64 + (p << 3);
    }
    const u16* gB[NIB]; int lB[NIB];
    #pragma unroll
    for (int i = 0; i < NIB; ++i) {
        const int cid = (i << 6) + lane;
        const int rl = cid >> 3, p = cid & 7, q = p ^ (rl & 7);
        gB[i] = Bt + (colbase + (wave << 4) + rl) * (long)K + (q << 3);
        lB[i] = ((wave << 4) + rl) * 64 + (p << 3);
    }

    floatx4 acc[MS][4];
    #pragma unroll
    for (int i = 0; i < MS; ++i)
        #pragma unroll
        for (int j = 0; j < 4; ++j)
            acc[i][j] = floatx4{0.f, 0.f, 0.f, 0.f};

    for (int k0 = 0; k0 < K; k0 += 64) {
        __syncthreads();
        #pragma unroll
        for (int i = 0; i < 4; ++i) { gld_lds16(gA[i], As + lA[i]); gA[i] += 64; }
        #pragma unroll
        for (int i = 0; i < NIB; ++i) { gld_lds16(gB[i], Bs + lB[i]); gB[i] += 64; }
        __syncthreads();
        #pragma unroll
        for (int kc = 0; kc < 2; ++kc) {
            const int ph = (((kc << 2) + quad) ^ sl) << 3;
            bf16x8 af[MS], bf[4];
            #pragma unroll
            for (int ms = 0; ms < MS; ++ms)
                af[ms] = *(const bf16x8*)&As[(wm + (ms << 4) + lrow) * 64 + ph];
            #pragma unroll
            for (int ns = 0; ns < 4; ++ns)
                bf[ns] = *(const bf16x8*)&Bs[(wn + (ns << 4) + lrow) * 64 + ph];
            #pragma unroll
            for (int ms = 0; ms < MS; ++ms)
                #pragma unroll
                for (int ns = 0; ns < 4; ++ns)
                    acc[ms][ns] = __builtin_amdgcn_mfma_f32_16x16x32_bf16(
                        af[ms], bf[ns], acc[ms][ns], 0, 0, 0);
        }
    }

    #pragma unroll
    for (int ms = 0; ms < MS; ++ms) {
        #pragma unroll
        for (int ns = 0; ns < 4; ++ns) {
            const long col = colbase + wn + (ns << 4) + lrow;
            const float bv = bias0[col];
            #pragma unroll
            for (int r = 0; r < 4; ++r) {
                const long row = rowbase + wm + (ms << 4) + (quad << 2) + r;
                const long idx = row * M + col;
                out[idx] = acc[ms][ns][r] + bv + res[idx];
            }
        }
    }
}

// ---------------------------------------------------------------------------
// Flash attention v12 = v11 + Ps re-layout: stride 72 u16 (144B rows, 8-way
// read conflict -> 3.1M SQ_LDS_BANK_CONFLICT, ~10% of dispatch) replaced by
// the GEMM-proven stride-64 + 16B-chunk XOR layout (measures 0 conflicts in
// every GEMM dispatch of this binary). Write granule g=4ns+quad at
// ((g>>1 ^ sl)<<3)+((g&1)<<2); read chunk c at ((c^sl)<<3).
// ---------------------------------------------------------------------------
__global__ __launch_bounds__(512) void attn_kernel(
    const u16* __restrict__ Q, const u16* __restrict__ Kp,
    const u16* __restrict__ Vt, u16* __restrict__ O)
{
    __shared__ u16 Ks[2][4096];       // 16 KB (dbuf)
    __shared__ u16 Vs[2][4096];       // 16 KB (dbuf)
    __shared__ u16 Ps[8][16][64];     // 16 KB (XOR-swizzled)
    const int tid = threadIdx.x, lane = tid & 63, wave = tid >> 6;
    const int lrow = lane & 15, quad = lane >> 4;
    const int psl = lrow & 7;

    // XCD-bijective swizzle: lin -> (xcd chunk of 64) -> 4 heads per XCD.
    const int lin = blockIdx.x;
    const int nl  = ((lin & 7) << 6) + (lin >> 3);
    const int bh  = nl >> 4;
    const int qt  = nl & 15;
    const long kvbase = (long)bh * 2048 * 64;
    const int qbase = (qt << 7) + (wave << 4);

    // Staging: wave role split. c = quarter index (16 rows of the 64-row tile).
    const int srow = lane >> 3;
    const int schunk = (lane & 7) ^ srow;
    const int c = wave & 3;
    const bool isV = wave >= 4;
    const int lofs = c << 10;
    const u16* g0 = isV
        ? (Vt + kvbase + (long)(((c << 4) + srow) * 2048 + (schunk << 3)))
        : (Kp + kvbase + (long)(((c << 4) + srow) * 64   + (schunk << 3)));
    const u16* g1 = g0 + (isV ? 8 * 2048 : 8 * 64);
    const int gstep = isV ? 64 : 4096;
    u16* lb0 = isV ? &Vs[0][lofs] : &Ks[0][lofs];
    u16* lb1 = isV ? &Vs[1][lofs] : &Ks[1][lofs];

    bf16x8 qf[2];
    #pragma unroll
    for (int h = 0; h < 2; ++h)
        qf[h] = *(const bf16x8*)(Q + kvbase +
            (long)(qbase + lrow) * 64 + (quad << 3) + (h << 5));

    int aoff[4][2];
    #pragma unroll
    for (int ns = 0; ns < 4; ++ns)
        #pragma unroll
        for (int h = 0; h < 2; ++h)
            aoff[ns][h] = ((ns << 4) + lrow) * 64 +
                          (((quad + (h << 2)) ^ (lrow & 7)) << 3);

    // Ps swizzled offsets (u16 indices within Ps[wave][lrow]):
    int pwoff[4];   // write: granule g = 4ns+quad
    #pragma unroll
    for (int ns = 0; ns < 4; ++ns) {
        const int g = (ns << 2) + quad;
        pwoff[ns] = (((g >> 1) ^ psl) << 3) + ((g & 1) << 2);
    }
    const int proff0 = ((quad ^ psl) << 3);            // read chunk quad
    const int proff1 = (((quad + 4) ^ psl) << 3);      // read chunk quad+4

    floatx4 oacc[4];
    #pragma unroll
    for (int ns = 0; ns < 4; ++ns)
        oacc[ns] = floatx4{0.f, 0.f, 0.f, 0.f};
    float lr = 0.f;

    gld_lds16(g0, lb0);
    gld_lds16(g1, lb0 + 512);
    g0 += gstep; g1 += gstep;

    for (int it = 0; it < 32; ++it) {
        const int cur = it & 1;
        __syncthreads();
        if (it < 31) {
            u16* dst = cur ? lb0 : lb1;
            gld_lds16(g0, dst);
            gld_lds16(g1, dst + 512);
            g0 += gstep; g1 += gstep;
        }
        const u16* ks = &Ks[cur][0];
        const u16* vs = &Vs[cur][0];

        floatx4 st[4];
        __builtin_amdgcn_s_setprio(1);
        #pragma unroll
        for (int ns = 0; ns < 4; ++ns) {
            const bf16x8 af0 = *(const bf16x8*)&ks[aoff[ns][0]];
            const bf16x8 af1 = *(const bf16x8*)&ks[aoff[ns][1]];
            floatx4 z = floatx4{0.f, 0.f, 0.f, 0.f};
            st[ns] = __builtin_amdgcn_mfma_f32_16x16x32_bf16(af0, qf[0], z, 0, 0, 0);
            st[ns] = __builtin_amdgcn_mfma_f32_16x16x32_bf16(af1, qf[1], st[ns], 0, 0, 0);
        }
        __builtin_amdgcn_s_setprio(0);

        float rs = 0.f;
        #pragma unroll
        for (int ns = 0; ns < 4; ++ns) {
            const float p0 = __builtin_amdgcn_exp2f(st[ns][0]);
            const float p1 = __builtin_amdgcn_exp2f(st[ns][1]);
            const float p2 = __builtin_amdgcn_exp2f(st[ns][2]);
            const float p3 = __builtin_amdgcn_exp2f(st[ns][3]);
            rs += (p0 + p1) + (p2 + p3);
            uint2 w;
            asm("v_cvt_pk_bf16_f32 %0, %1, %2" : "=v"(w.x) : "v"(p0), "v"(p1));
            asm("v_cvt_pk_bf16_f32 %0, %1, %2" : "=v"(w.y) : "v"(p2), "v"(p3));
            *(uint2*)&Ps[wave][lrow][pwoff[ns]] = w;
        }
        rs += __shfl_xor(rs, 16);
        rs += __shfl_xor(rs, 32);
        lr += rs;
        const bf16x8 pf0 = *(const bf16x8*)&Ps[wave][lrow][proff0];
        const bf16x8 pf1 = *(const bf16x8*)&Ps[wave][lrow][proff1];

        __builtin_amdgcn_s_setprio(1);
        #pragma unroll
        for (int ns = 0; ns < 4; ++ns) {
            const bf16x8 vf0 = *(const bf16x8*)&vs[aoff[ns][0]];
            const bf16x8 vf1 = *(const bf16x8*)&vs[aoff[ns][1]];
            oacc[ns] = __builtin_amdgcn_mfma_f32_16x16x32_bf16(pf0, vf0, oacc[ns], 0, 0, 0);
            oacc[ns] = __builtin_amdgcn_mfma_f32_16x16x32_bf16(pf1, vf1, oacc[ns], 0, 0, 0);
        }
        __builtin_amdgcn_s_setprio(0);
    }

    const int b = bh >> 4, h = bh & 15;
    float linv[4];
    #pragma unroll
    for (int r = 0; r < 4; ++r)
        linv[r] = 1.0f / __shfl(lr, (quad << 2) + r);
    #pragma unroll
    for (int ns = 0; ns < 4; ++ns)
        #pragma unroll
        for (int r = 0; r < 4; ++r) {
            const int q = qbase + (quad << 2) + r;
            const long token = (long)b * 2048 + q;
            O[token * 1024 + (h << 6) + (ns << 4) + lrow] =
                f2bf(oacc[ns][r] * linv[r]);
        }
}

// ---------------------------------------------------------------------------
// Host launcher
// ---------------------------------------------------------------------------
extern "C" void kernel_launch(void* const* d_in, const int* in_sizes, int n_in,
                              void* d_out, int out_size, void* d_ws, size_t ws_size,
                              hipStream_t stream)
{
    const float* x     = (const float*)d_in[0];
    const float* ln1_g = (const float*)d_in[1];
    const float* ln1_b = (const float*)d_in[2];
    const float* wq    = (const float*)d_in[3];
    const float* bq    = (const float*)d_in[4];
    const float* wk    = (const float*)d_in[5];
    const float* bk    = (const float*)d_in[6];
    const float* wv    = (const float*)d_in[7];
    const float* bv    = (const float*)d_in[8];
    const float* wo    = (const float*)d_in[9];
    const float* bo    = (const float*)d_in[10];
    const float* w1    = (const float*)d_in[11];
    const float* b1    = (const float*)d_in[12];
    const float* w2    = (const float*)d_in[13];
    const float* b2    = (const float*)d_in[14];
    const float* ln2_g = (const float*)d_in[15];
    const float* ln2_b = (const float*)d_in[16];
    float* out = (float*)d_out;

    char* w = (char*)d_ws;
    const size_t MB = 1024 * 1024;
    u16*   wqkvt = (u16*)(w + 0);        // [0,6) MB
    u16*   wot   = (u16*)(w + 6  * MB);  // [6,8)
    u16*   w1t   = (u16*)(w + 8  * MB);  // [8,16)
    u16*   w2t   = (u16*)(w + 16 * MB);  // [16,24)
    u16*   h1    = (u16*)(w + 24 * MB);  // [24,32): ln1 / attn-out / ln2
    u16*   qkvb  = (u16*)(w + 32 * MB);  // [32,56): Q|K|V (bh,s,d)
    u16*   vtb   = (u16*)(w + 56 * MB);  // [56,64): V^T (bh,d,s)
    float* x1    = (float*)(w + 64 * MB);// [64,80): fp32 residual-1
    float* part1 = (float*)(w + 80 * MB);// [80,96): FF2 split-K partial z=1
    u16*   ffb   = (u16*)(w + 32 * MB);  // [32,64): FF hidden (reuses qkv/vtb)
    u16*   qb = qkvb;
    u16*   kb = qkvb + 4194304;
    u16*   vb = qkvb + 8388608;

    transpose_cvt4<<<dim3(32, 32, 4), 256, 0, stream>>>(
        wq, wk, wv, wo, wqkvt, wqkvt + 1048576, wqkvt + 2097152, wot);
    transpose_cvt<<<dim3(128, 32), 256, 0, stream>>>(w1, w1t, 1024, 4096);
    transpose_cvt<<<dim3(32, 128), 256, 0, stream>>>(w2, w2t, 4096, 1024);

    ln_kernel<<<4096, 256, 0, stream>>>(x, ln1_g, ln1_b, h1);

    // QKV: 4096x3072, K=1024. 256^2 tiles -> 192 blocks.
    gemm256_kernel<0><<<dim3(12, 16), 512, 0, stream>>>(
        h1, wqkvt, bq, bk, bv, qkvb, 1024, 3072);

    vtrans_kernel<<<dim3(32, 32), 256, 0, stream>>>(vb, vtb);

    attn_kernel<<<dim3(512), 512, 0, stream>>>(qb, kb, vtb, h1);

    // O-proj: 4096x1024, K=1024. 128x64 single-buffer, high TLP.
    gemm_oproj_kernel<<<dim3(16, 32), 256, 0, stream>>>(
        h1, wot, bo, x, x1, 1024, 1024);

    ln_kernel<<<4096, 256, 0, stream>>>(x1, ln2_g, ln2_b, h1);

    // FF1: 4096x4096, K=1024. 256^2 tiles -> 256 blocks = 1/CU.
    gemm256_kernel<2><<<dim3(16, 16), 512, 0, stream>>>(
        h1, w1t, b1, nullptr, nullptr, ffb, 1024, 4096);

    // FF2: 4096x1024, K=4096. 128^2 8-wave dbuf split-K=2 -> 512 blocks.
    gemm_ff2_kernel<<<dim3(8, 32, 2), 512, 0, stream>>>(
        ffb, w2t, b2, x1, part1, out, 4096, 1024);

    add_kernel<<<4096, 256, 0, stream>>>(out, part1);
}

// Round 13
// 342.747 us; speedup vs baseline: 1.0824x; 1.0053x over previous
//
#include <hip/hip_runtime.h>

typedef unsigned short u16;
typedef unsigned int u32;
typedef __bf16 bf16x8 __attribute__((ext_vector_type(8)));
typedef float floatx4 __attribute__((ext_vector_type(4)));

__device__ __forceinline__ u16 f2bf(float f) {
    u32 u = __float_as_uint(f);
    u = (u + 0x7FFFu + ((u >> 16) & 1u)) >> 16;
    return (u16)u;
}

__device__ __forceinline__ void gld_lds16(const u16* g, u16* l) {
    __builtin_amdgcn_global_load_lds(
        (const __attribute__((address_space(1))) u32*)g,
        (__attribute__((address_space(3))) u32*)l, 16, 0, 0);
}

// Exact-enough GELU: erf via Abramowitz-Stegun 7.1.26 (|err| < 1.5e-7).
__device__ __forceinline__ float gelu_exact(float v) {
    const float z = fabsf(v) * 0.70710678118f;
    const float t = __builtin_amdgcn_rcpf(1.0f + 0.3275911f * z);
    const float e = __builtin_amdgcn_exp2f(-z * z * 1.44269504f);
    float poly = 1.061405429f;
    poly = poly * t - 1.453152027f;
    poly = poly * t + 1.421413741f;
    poly = poly * t - 0.284496736f;
    poly = poly * t + 0.254829592f;
    float erfz = 1.0f - poly * t * e;
    erfz = copysignf(erfz, v);
    return 0.5f * v * (1.0f + erfz);
}

// ---------------------------------------------------------------------------
// Four 1024x1024 transposes + fp32->bf16 in one launch (z picks the matrix).
// ---------------------------------------------------------------------------
__global__ __launch_bounds__(256) void transpose_cvt4(
    const float* __restrict__ s0, const float* __restrict__ s1,
    const float* __restrict__ s2, const float* __restrict__ s3,
    u16* __restrict__ d0, u16* __restrict__ d1,
    u16* __restrict__ d2, u16* __restrict__ d3)
{
    __shared__ float t[32][33];
    const int z = blockIdx.z;
    const float* src = z == 0 ? s0 : (z == 1 ? s1 : (z == 2 ? s2 : s3));
    u16* dst = z == 0 ? d0 : (z == 1 ? d1 : (z == 2 ? d2 : d3));
    const int bm = blockIdx.x * 32, bk = blockIdx.y * 32;
    const int tx = threadIdx.x & 31, ty = threadIdx.x >> 5;
    #pragma unroll
    for (int i = ty; i < 32; i += 8)
        t[i][tx] = src[(long)(bk + i) * 1024 + bm + tx];
    __syncthreads();
    #pragma unroll
    for (int i = ty; i < 32; i += 8)
        dst[(long)(bm + i) * 1024 + bk + tx] = f2bf(t[tx][i]);
}

// ---------------------------------------------------------------------------
// Transpose + fp32->bf16: src K x M -> dst M x K.
// ---------------------------------------------------------------------------
__global__ __launch_bounds__(256) void transpose_cvt(
    const float* __restrict__ src, u16* __restrict__ dst, int K, int M)
{
    __shared__ float t[32][33];
    const int bm = blockIdx.x * 32, bk = blockIdx.y * 32;
    const int tx = threadIdx.x & 31, ty = threadIdx.x >> 5;
    #pragma unroll
    for (int i = ty; i < 32; i += 8)
        t[i][tx] = src[(long)(bk + i) * M + bm + tx];
    __syncthreads();
    #pragma unroll
    for (int i = ty; i < 32; i += 8)
        dst[(long)(bm + i) * K + bk + tx] = f2bf(t[tx][i]);
}

// ---------------------------------------------------------------------------
// LayerNorm over rows of 1024 fp32 -> bf16. One block per row.
// ---------------------------------------------------------------------------
__global__ __launch_bounds__(256) void ln_kernel(
    const float* __restrict__ x, const float* __restrict__ g,
    const float* __restrict__ bta, u16* __restrict__ out)
{
    const int row = blockIdx.x;
    const int tid = threadIdx.x;
    const float4 v = ((const float4*)(x + (long)row * 1024))[tid];
    float s  = v.x + v.y + v.z + v.w;
    float s2 = v.x*v.x + v.y*v.y + v.z*v.z + v.w*v.w;
    #pragma unroll
    for (int off = 1; off < 64; off <<= 1) {
        s  += __shfl_xor(s, off);
        s2 += __shfl_xor(s2, off);
    }
    __shared__ float red[8];
    const int wave = tid >> 6, lane = tid & 63;
    if (lane == 0) { red[wave] = s; red[4 + wave] = s2; }
    __syncthreads();
    s  = red[0] + red[1] + red[2] + red[3];
    s2 = red[4] + red[5] + red[6] + red[7];
    const float mu   = s * (1.0f / 1024.0f);
    const float var  = s2 * (1.0f / 1024.0f) - mu * mu;
    const float rstd = rsqrtf(var + 1e-5f);
    const int c = tid << 2;
    ushort4 o;
    o.x = f2bf((v.x - mu) * rstd * g[c + 0] + bta[c + 0]);
    o.y = f2bf((v.y - mu) * rstd * g[c + 1] + bta[c + 1]);
    o.z = f2bf((v.z - mu) * rstd * g[c + 2] + bta[c + 2]);
    o.w = f2bf((v.w - mu) * rstd * g[c + 3] + bta[c + 3]);
    ((ushort4*)(out + (long)row * 1024))[tid] = o;
}

// ---------------------------------------------------------------------------
// Split-K combine: out[i] += p1[i].
// ---------------------------------------------------------------------------
__global__ __launch_bounds__(256) void add_kernel(
    float* __restrict__ out, const float* __restrict__ p1)
{
    const int t = blockIdx.x * 256 + threadIdx.x;
    const float4 a = ((const float4*)out)[t];
    const float4 c = ((const float4*)p1)[t];
    float4 o;
    o.x = a.x + c.x;
    o.y = a.y + c.y;
    o.z = a.z + c.z;
    o.w = a.w + c.w;
    ((float4*)out)[t] = o;
}

// ---------------------------------------------------------------------------
// V transpose per (b,h): (bh, s=2048, d=64) -> (bh, d=64, s=2048), bf16.
// ---------------------------------------------------------------------------
__global__ __launch_bounds__(256) void vtrans_kernel(
    const u16* __restrict__ V, u16* __restrict__ Vt)
{
    __shared__ u16 t[64][72];
    const int bh = blockIdx.y, s0 = blockIdx.x << 6;
    const int tid = threadIdx.x;
    const long base = (long)bh * 2048 * 64;
    const int row = tid >> 2, seg = tid & 3;
    *(uint4*)&t[row][seg << 3] =
        *(const uint4*)(V + base + (long)(s0 + row) * 64 + (seg << 3));
    *(uint4*)&t[row][(seg + 4) << 3] =
        *(const uint4*)(V + base + (long)(s0 + row) * 64 + ((seg + 4) << 3));
    __syncthreads();
    #pragma unroll
    for (int half = 0; half < 2; ++half) {
        const int sl = (seg + (half << 2)) << 3;
        u16 tmp[8];
        #pragma unroll
        for (int j = 0; j < 8; ++j) tmp[j] = t[sl + j][row];
        *(uint4*)(Vt + base + (long)row * 2048 + s0 + sl) = *(uint4*)tmp;
    }
}

// ---------------------------------------------------------------------------
// 256x256-tile GEMM, BK=64, 8 waves (512 thr), dbuf LDS (128 KB, 1 blk/CU),
// early-issue staging, setprio around MFMA clusters.
// XCD swizzle v2: 2D chunk. Each XCD owns a (gx/4)x(gy/2) sub-grid so its
// B working set (cbx panels, 2 MB @ FF1) FITS its 4 MB private L2 instead
// of streaming all 16 panels (8 MB, thrash). Theory: staging is L2/HBM-BW
// bound (64 KB/iter vs ~640 cyc compute), so B-residency is the lever.
// MODE 0: out bf16, fused QKV scatter; Q pre-scaled by 0.125*log2(e)
// MODE 2: out bf16 row-major, gelu(v+bias)
// ---------------------------------------------------------------------------
template<int MODE>
__global__ __launch_bounds__(512, 2) void gemm256_kernel(
    const u16* __restrict__ A, const u16* __restrict__ Bt,
    const float* __restrict__ bias0, const float* __restrict__ bias1,
    const float* __restrict__ bias2, void* __restrict__ outv, int K, int M)
{
    __shared__ u16 As[2][256 * 64];   // 32 KB each
    __shared__ u16 Bs[2][256 * 64];   // 32 KB each
    const int tid = threadIdx.x, lane = tid & 63, wave = tid >> 6;
    const int wr = wave >> 2, wc = wave & 3;
    const int lrow = lane & 15, quad = lane >> 4, sl = lrow & 7;

    // 2D XCD-chunked swizzle (gx%4==0, gy%2==0 for our launches; bijective).
    const int cbx = gridDim.x >> 2, cby = gridDim.y >> 1;
    const int lin = blockIdx.x + gridDim.x * blockIdx.y;
    const int xcd = lin & 7, idx = lin >> 3;
    const int bx = (xcd & 3) * cbx + idx % cbx;
    const int by = (xcd >> 2) * cby + idx / cbx;

    const long rowbase = (long)by * 256;
    const long colbase = (long)bx * 256;

    const u16* gA[4]; int lA[4];
    const u16* gB[4]; int lB[4];
    #pragma unroll
    for (int i = 0; i < 4; ++i) {
        const int cid = (i << 9) + tid;
        const int rl = cid >> 3, p = cid & 7, q = p ^ (rl & 7);
        gA[i] = A  + (rowbase + rl) * (long)K + (q << 3);
        gB[i] = Bt + (colbase + rl) * (long)K + (q << 3);
        lA[i] = rl * 64 + (p << 3);
        lB[i] = rl * 64 + (p << 3);
    }

    floatx4 acc[8][4];
    #pragma unroll
    for (int i = 0; i < 8; ++i)
        #pragma unroll
        for (int j = 0; j < 4; ++j)
            acc[i][j] = floatx4{0.f, 0.f, 0.f, 0.f};

    #pragma unroll
    for (int i = 0; i < 4; ++i) { gld_lds16(gA[i], As[0] + lA[i]); gA[i] += 64; }
    #pragma unroll
    for (int i = 0; i < 4; ++i) { gld_lds16(gB[i], Bs[0] + lB[i]); gB[i] += 64; }
    asm volatile("s_waitcnt vmcnt(0)" ::: "memory");
    __builtin_amdgcn_s_barrier();
    __builtin_amdgcn_sched_barrier(0);

    const int niter = K >> 6;
    int cur = 0;
    for (int t = 0; t < niter; ++t) {
        if (t + 1 < niter) {
            #pragma unroll
            for (int i = 0; i < 4; ++i) { gld_lds16(gA[i], As[cur ^ 1] + lA[i]); gA[i] += 64; }
            #pragma unroll
            for (int i = 0; i < 4; ++i) { gld_lds16(gB[i], Bs[cur ^ 1] + lB[i]); gB[i] += 64; }
        }

        const u16* as = As[cur];
        const u16* bs = Bs[cur];

        bf16x8 bfr[4][2];
        #pragma unroll
        for (int ns = 0; ns < 4; ++ns)
            #pragma unroll
            for (int kc = 0; kc < 2; ++kc)
                bfr[ns][kc] = *(const bf16x8*)
                    &bs[((wc << 6) + (ns << 4) + lrow) * 64 + ((((kc << 2) + quad) ^ sl) << 3)];

        #pragma unroll
        for (int p = 0; p < 4; ++p) {
            bf16x8 af[2][2];
            #pragma unroll
            for (int m = 0; m < 2; ++m)
                #pragma unroll
                for (int kc = 0; kc < 2; ++kc)
                    af[m][kc] = *(const bf16x8*)
                        &as[((wr << 7) + ((p * 2 + m) << 4) + lrow) * 64 + ((((kc << 2) + quad) ^ sl) << 3)];
            __builtin_amdgcn_s_setprio(1);
            #pragma unroll
            for (int kc = 0; kc < 2; ++kc)
                #pragma unroll
                for (int m = 0; m < 2; ++m)
                    #pragma unroll
                    for (int ns = 0; ns < 4; ++ns)
                        acc[p * 2 + m][ns] = __builtin_amdgcn_mfma_f32_16x16x32_bf16(
                            af[m][kc], bfr[ns][kc], acc[p * 2 + m][ns], 0, 0, 0);
            __builtin_amdgcn_s_setprio(0);
        }

        asm volatile("s_waitcnt lgkmcnt(0)" ::: "memory");
        asm volatile("s_waitcnt vmcnt(0)" ::: "memory");
        __builtin_amdgcn_s_barrier();
        __builtin_amdgcn_sched_barrier(0);
        cur ^= 1;
    }

    #pragma unroll
    for (int ms = 0; ms < 8; ++ms) {
        #pragma unroll
        for (int ns = 0; ns < 4; ++ns) {
            const long col = colbase + (wc << 6) + (ns << 4) + lrow;
            float bv;
            if constexpr (MODE == 0) {
                const int which = (int)(col >> 10);
                const float* bp = which == 0 ? bias0 : (which == 1 ? bias1 : bias2);
                bv = bp[col & 1023];
            } else {
                bv = bias0[col];
            }
            #pragma unroll
            for (int r = 0; r < 4; ++r) {
                const long row = rowbase + (wr << 7) + (ms << 4) + (quad << 2) + r;
                float v = acc[ms][ns][r] + bv;
                if constexpr (MODE == 0) {
                    const long which = col >> 10;
                    if (which == 0) v *= 0.18033688f;   // 0.125*log2(e) into Q
                    const long b = row >> 11, s = row & 2047;
                    const long h = (col >> 6) & 15, d = col & 63;
                    ((u16*)outv)[which * 4194304 + (((b << 4) + h) * 2048 + s) * 64 + d] = f2bf(v);
                } else {
                    ((u16*)outv)[row * M + col] = f2bf(gelu_exact(v));
                }
            }
        }
    }
}

// ---------------------------------------------------------------------------
// FF2: 128x128-tile split-K=2, 8 waves x (64x32 output) = 512 threads.
// z=0 -> out (+bias+res folded), z=1 -> part1; add_kernel combines.
// ---------------------------------------------------------------------------
__global__ __launch_bounds__(512, 2) void gemm_ff2_kernel(
    const u16* __restrict__ A, const u16* __restrict__ Bt,
    const float* __restrict__ bias0, const float* __restrict__ res,
    float* __restrict__ part1, float* __restrict__ out, int K, int M)
{
    __shared__ u16 As[2][128 * 64];   // 16 KB each
    __shared__ u16 Bs[2][128 * 64];   // 16 KB each
    const int tid = threadIdx.x, lane = tid & 63, wave = tid >> 6;
    const int wr = wave >> 2, wc = wave & 3;
    const int lrow = lane & 15, quad = lane >> 4, sl = lrow & 7;

    const int nwg = gridDim.x * gridDim.y * gridDim.z;
    const int lin = blockIdx.x + gridDim.x * (blockIdx.y + gridDim.y * blockIdx.z);
    const int wg  = (lin & 7) * (nwg >> 3) + (lin >> 3);
    const int bx  = wg % gridDim.x;
    const int rest = wg / gridDim.x;
    const int by  = rest % gridDim.y;
    const int bz  = rest / gridDim.y;

    const long rowbase = (long)by * 128;
    const long colbase = (long)bx * 128;
    const int kstart = bz * (K >> 1);
    const int kend   = kstart + (K >> 1);

    const u16* gA[2]; int lA[2];
    const u16* gB[2]; int lB[2];
    #pragma unroll
    for (int i = 0; i < 2; ++i) {
        const int cid = (i << 9) + tid;
        const int rl = cid >> 3, p = cid & 7, q = p ^ (rl & 7);
        gA[i] = A  + (rowbase + rl) * (long)K + kstart + (q << 3);
        gB[i] = Bt + (colbase + rl) * (long)K + kstart + (q << 3);
        lA[i] = rl * 64 + (p << 3);
        lB[i] = rl * 64 + (p << 3);
    }

    floatx4 acc[4][2];
    #pragma unroll
    for (int i = 0; i < 4; ++i)
        #pragma unroll
        for (int j = 0; j < 2; ++j)
            acc[i][j] = floatx4{0.f, 0.f, 0.f, 0.f};

    #pragma unroll
    for (int i = 0; i < 2; ++i) { gld_lds16(gA[i], As[0] + lA[i]); gA[i] += 64; }
    #pragma unroll
    for (int i = 0; i < 2; ++i) { gld_lds16(gB[i], Bs[0] + lB[i]); gB[i] += 64; }
    asm volatile("s_waitcnt vmcnt(0)" ::: "memory");
    __builtin_amdgcn_s_barrier();
    __builtin_amdgcn_sched_barrier(0);

    const int niter = (kend - kstart) >> 6;
    int cur = 0;
    for (int t = 0; t < niter; ++t) {
        if (t + 1 < niter) {
            #pragma unroll
            for (int i = 0; i < 2; ++i) { gld_lds16(gA[i], As[cur ^ 1] + lA[i]); gA[i] += 64; }
            #pragma unroll
            for (int i = 0; i < 2; ++i) { gld_lds16(gB[i], Bs[cur ^ 1] + lB[i]); gB[i] += 64; }
        }

        const u16* as = As[cur];
        const u16* bs = Bs[cur];

        bf16x8 bfr[2][2], af[4][2];
        #pragma unroll
        for (int ns = 0; ns < 2; ++ns)
            #pragma unroll
            for (int kc = 0; kc < 2; ++kc)
                bfr[ns][kc] = *(const bf16x8*)
                    &bs[((wc << 5) + (ns << 4) + lrow) * 64 + ((((kc << 2) + quad) ^ sl) << 3)];
        #pragma unroll
        for (int m = 0; m < 4; ++m)
            #pragma unroll
            for (int kc = 0; kc < 2; ++kc)
                af[m][kc] = *(const bf16x8*)
                    &as[((wr << 6) + (m << 4) + lrow) * 64 + ((((kc << 2) + quad) ^ sl) << 3)];

        __builtin_amdgcn_s_setprio(1);
        #pragma unroll
        for (int kc = 0; kc < 2; ++kc)
            #pragma unroll
            for (int m = 0; m < 4; ++m)
                #pragma unroll
                for (int ns = 0; ns < 2; ++ns)
                    acc[m][ns] = __builtin_amdgcn_mfma_f32_16x16x32_bf16(
                        af[m][kc], bfr[ns][kc], acc[m][ns], 0, 0, 0);
        __builtin_amdgcn_s_setprio(0);

        asm volatile("s_waitcnt lgkmcnt(0)" ::: "memory");
        asm volatile("s_waitcnt vmcnt(0)" ::: "memory");
        __builtin_amdgcn_s_barrier();
        __builtin_amdgcn_sched_barrier(0);
        cur ^= 1;
    }

    float* tgt = bz ? part1 : out;
    #pragma unroll
    for (int m = 0; m < 4; ++m) {
        #pragma unroll
        for (int ns = 0; ns < 2; ++ns) {
            const long col = colbase + (wc << 5) + (ns << 4) + lrow;
            #pragma unroll
            for (int r = 0; r < 4; ++r) {
                const long row = rowbase + (wr << 6) + (m << 4) + (quad << 2) + r;
                const long idx = row * M + col;
                float v = acc[m][ns][r];
                if (bz == 0)
                    tgt[idx] = v + bias0[col] + res[idx];  // fold b2 + residual
                else
                    tgt[idx] = v;
            }
        }
    }
}

// ---------------------------------------------------------------------------
// 128x64 GEMM (O-proj): single-buffer 2-phase, 24 KB LDS -> high TLP.
// out fp32 row-major, +bias +res.
// ---------------------------------------------------------------------------
__global__ __launch_bounds__(256) void gemm_oproj_kernel(
    const u16* __restrict__ A, const u16* __restrict__ Bt,
    const float* __restrict__ bias0, const float* __restrict__ res,
    float* __restrict__ out, int K, int M)
{
    constexpr int MS = 2, NIB = 2;
    __shared__ u16 As[128 * 64];
    __shared__ u16 Bs[64 * 64];
    const int tid = threadIdx.x, lane = tid & 63, wave = tid >> 6;
    const int wm = wave << 5, wn = 0;
    const int lrow = lane & 15, quad = lane >> 4;
    const int sl = lrow & 7;

    const int nwg = gridDim.x * gridDim.y;
    const int lin = blockIdx.x + gridDim.x * blockIdx.y;
    const int wg  = (lin & 7) * (nwg >> 3) + (lin >> 3);
    const int bx  = wg % gridDim.x;
    const int by  = wg / gridDim.x;

    const long rowbase = (long)by * 128;
    const long colbase = (long)bx * 64;

    const u16* gA[4]; int lA[4];
    #pragma unroll
    for (int i = 0; i < 4; ++i) {
        const int cid = (i << 6) + lane;
        const int rl = cid >> 3, p = cid & 7, q = p ^ (rl & 7);
        gA[i] = A + (rowbase + (wave << 5) + rl) * (long)K + (q << 3);
        lA[i] = ((wave << 5) + rl) * 64 + (p << 3);
    }
    const u16* gB[NIB]; int lB[NIB];
    #pragma unroll
    for (int i = 0; i < NIB; ++i) {
        const int cid = (i << 6) + lane;
        const int rl = cid >> 3, p = cid & 7, q = p ^ (rl & 7);
        gB[i] = Bt + (colbase + (wave << 4) + rl) * (long)K + (q << 3);
        lB[i] = ((wave << 4) + rl) * 64 + (p << 3);
    }

    floatx4 acc[MS][4];
    #pragma unroll
    for (int i = 0; i < MS; ++i)
        #pragma unroll
        for (int j = 0; j < 4; ++j)
            acc[i][j] = floatx4{0.f, 0.f, 0.f, 0.f};

    for (int k0 = 0; k0 < K; k0 += 64) {
        __syncthreads();
        #pragma unroll
        for (int i = 0; i < 4; ++i) { gld_lds16(gA[i], As + lA[i]); gA[i] += 64; }
        #pragma unroll
        for (int i = 0; i < NIB; ++i) { gld_lds16(gB[i], Bs + lB[i]); gB[i] += 64; }
        __syncthreads();
        #pragma unroll
        for (int kc = 0; kc < 2; ++kc) {
            const int ph = (((kc << 2) + quad) ^ sl) << 3;
            bf16x8 af[MS], bf[4];
            #pragma unroll
            for (int ms = 0; ms < MS; ++ms)
                af[ms] = *(const bf16x8*)&As[(wm + (ms << 4) + lrow) * 64 + ph];
            #pragma unroll
            for (int ns = 0; ns < 4; ++ns)
                bf[ns] = *(const bf16x8*)&Bs[(wn + (ns << 4) + lrow) * 64 + ph];
            #pragma unroll
            for (int ms = 0; ms < MS; ++ms)
                #pragma unroll
                for (int ns = 0; ns < 4; ++ns)
                    acc[ms][ns] = __builtin_amdgcn_mfma_f32_16x16x32_bf16(
                        af[ms], bf[ns], acc[ms][ns], 0, 0, 0);
        }
    }

    #pragma unroll
    for (int ms = 0; ms < MS; ++ms) {
        #pragma unroll
        for (int ns = 0; ns < 4; ++ns) {
            const long col = colbase + wn + (ns << 4) + lrow;
            const float bv = bias0[col];
            #pragma unroll
            for (int r = 0; r < 4; ++r) {
                const long row = rowbase + wm + (ms << 4) + (quad << 2) + r;
                const long idx = row * M + col;
                out[idx] = acc[ms][ns][r] + bv + res[idx];
            }
        }
    }
}

// ---------------------------------------------------------------------------
// Flash attention v12 (r12 best: 51.6us): 8 waves x 16 q, dbuf KV, cvt_pk
// softmax pack, XOR-swizzled Ps, XCD swizzle.
// ---------------------------------------------------------------------------
__global__ __launch_bounds__(512) void attn_kernel(
    const u16* __restrict__ Q, const u16* __restrict__ Kp,
    const u16* __restrict__ Vt, u16* __restrict__ O)
{
    __shared__ u16 Ks[2][4096];       // 16 KB (dbuf)
    __shared__ u16 Vs[2][4096];       // 16 KB (dbuf)
    __shared__ u16 Ps[8][16][64];     // 16 KB (XOR-swizzled)
    const int tid = threadIdx.x, lane = tid & 63, wave = tid >> 6;
    const int lrow = lane & 15, quad = lane >> 4;
    const int psl = lrow & 7;

    // XCD-bijective swizzle: lin -> (xcd chunk of 64) -> 4 heads per XCD.
    const int lin = blockIdx.x;
    const int nl  = ((lin & 7) << 6) + (lin >> 3);
    const int bh  = nl >> 4;
    const int qt  = nl & 15;
    const long kvbase = (long)bh * 2048 * 64;
    const int qbase = (qt << 7) + (wave << 4);

    // Staging: wave role split. c = quarter index (16 rows of the 64-row tile).
    const int srow = lane >> 3;
    const int schunk = (lane & 7) ^ srow;
    const int c = wave & 3;
    const bool isV = wave >= 4;
    const int lofs = c << 10;
    const u16* g0 = isV
        ? (Vt + kvbase + (long)(((c << 4) + srow) * 2048 + (schunk << 3)))
        : (Kp + kvbase + (long)(((c << 4) + srow) * 64   + (schunk << 3)));
    const u16* g1 = g0 + (isV ? 8 * 2048 : 8 * 64);
    const int gstep = isV ? 64 : 4096;
    u16* lb0 = isV ? &Vs[0][lofs] : &Ks[0][lofs];
    u16* lb1 = isV ? &Vs[1][lofs] : &Ks[1][lofs];

    bf16x8 qf[2];
    #pragma unroll
    for (int h = 0; h < 2; ++h)
        qf[h] = *(const bf16x8*)(Q + kvbase +
            (long)(qbase + lrow) * 64 + (quad << 3) + (h << 5));

    int aoff[4][2];
    #pragma unroll
    for (int ns = 0; ns < 4; ++ns)
        #pragma unroll
        for (int h = 0; h < 2; ++h)
            aoff[ns][h] = ((ns << 4) + lrow) * 64 +
                          (((quad + (h << 2)) ^ (lrow & 7)) << 3);

    // Ps swizzled offsets (u16 indices within Ps[wave][lrow]):
    int pwoff[4];   // write: granule g = 4ns+quad
    #pragma unroll
    for (int ns = 0; ns < 4; ++ns) {
        const int g = (ns << 2) + quad;
        pwoff[ns] = (((g >> 1) ^ psl) << 3) + ((g & 1) << 2);
    }
    const int proff0 = ((quad ^ psl) << 3);            // read chunk quad
    const int proff1 = (((quad + 4) ^ psl) << 3);      // read chunk quad+4

    floatx4 oacc[4];
    #pragma unroll
    for (int ns = 0; ns < 4; ++ns)
        oacc[ns] = floatx4{0.f, 0.f, 0.f, 0.f};
    float lr = 0.f;

    gld_lds16(g0, lb0);
    gld_lds16(g1, lb0 + 512);
    g0 += gstep; g1 += gstep;

    for (int it = 0; it < 32; ++it) {
        const int cur = it & 1;
        __syncthreads();
        if (it < 31) {
            u16* dst = cur ? lb0 : lb1;
            gld_lds16(g0, dst);
            gld_lds16(g1, dst + 512);
            g0 += gstep; g1 += gstep;
        }
        const u16* ks = &Ks[cur][0];
        const u16* vs = &Vs[cur][0];

        floatx4 st[4];
        __builtin_amdgcn_s_setprio(1);
        #pragma unroll
        for (int ns = 0; ns < 4; ++ns) {
            const bf16x8 af0 = *(const bf16x8*)&ks[aoff[ns][0]];
            const bf16x8 af1 = *(const bf16x8*)&ks[aoff[ns][1]];
            floatx4 z = floatx4{0.f, 0.f, 0.f, 0.f};
            st[ns] = __builtin_amdgcn_mfma_f32_16x16x32_bf16(af0, qf[0], z, 0, 0, 0);
            st[ns] = __builtin_amdgcn_mfma_f32_16x16x32_bf16(af1, qf[1], st[ns], 0, 0, 0);
        }
        __builtin_amdgcn_s_setprio(0);

        float rs = 0.f;
        #pragma unroll
        for (int ns = 0; ns < 4; ++ns) {
            const float p0 = __builtin_amdgcn_exp2f(st[ns][0]);
            const float p1 = __builtin_amdgcn_exp2f(st[ns][1]);
            const float p2 = __builtin_amdgcn_exp2f(st[ns][2]);
            const float p3 = __builtin_amdgcn_exp2f(st[ns][3]);
            rs += (p0 + p1) + (p2 + p3);
            uint2 w;
            asm("v_cvt_pk_bf16_f32 %0, %1, %2" : "=v"(w.x) : "v"(p0), "v"(p1));
            asm("v_cvt_pk_bf16_f32 %0, %1, %2" : "=v"(w.y) : "v"(p2), "v"(p3));
            *(uint2*)&Ps[wave][lrow][pwoff[ns]] = w;
        }
        rs += __shfl_xor(rs, 16);
        rs += __shfl_xor(rs, 32);
        lr += rs;
        const bf16x8 pf0 = *(const bf16x8*)&Ps[wave][lrow][proff0];
        const bf16x8 pf1 = *(const bf16x8*)&Ps[wave][lrow][proff1];

        __builtin_amdgcn_s_setprio(1);
        #pragma unroll
        for (int ns = 0; ns < 4; ++ns) {
            const bf16x8 vf0 = *(const bf16x8*)&vs[aoff[ns][0]];
            const bf16x8 vf1 = *(const bf16x8*)&vs[aoff[ns][1]];
            oacc[ns] = __builtin_amdgcn_mfma_f32_16x16x32_bf16(pf0, vf0, oacc[ns], 0, 0, 0);
            oacc[ns] = __builtin_amdgcn_mfma_f32_16x16x32_bf16(pf1, vf1, oacc[ns], 0, 0, 0);
        }
        __builtin_amdgcn_s_setprio(0);
    }

    const int b = bh >> 4, h = bh & 15;
    float linv[4];
    #pragma unroll
    for (int r = 0; r < 4; ++r)
        linv[r] = 1.0f / __shfl(lr, (quad << 2) + r);
    #pragma unroll
    for (int ns = 0; ns < 4; ++ns)
        #pragma unroll
        for (int r = 0; r < 4; ++r) {
            const int q = qbase + (quad << 2) + r;
            const long token = (long)b * 2048 + q;
            O[token * 1024 + (h << 6) + (ns << 4) + lrow] =
                f2bf(oacc[ns][r] * linv[r]);
        }
}

// ---------------------------------------------------------------------------
// Host launcher
// ---------------------------------------------------------------------------
extern "C" void kernel_launch(void* const* d_in, const int* in_sizes, int n_in,
                              void* d_out, int out_size, void* d_ws, size_t ws_size,
                              hipStream_t stream)
{
    const float* x     = (const float*)d_in[0];
    const float* ln1_g = (const float*)d_in[1];
    const float* ln1_b = (const float*)d_in[2];
    const float* wq    = (const float*)d_in[3];
    const float* bq    = (const float*)d_in[4];
    const float* wk    = (const float*)d_in[5];
    const float* bk    = (const float*)d_in[6];
    const float* wv    = (const float*)d_in[7];
    const float* bv    = (const float*)d_in[8];
    const float* wo    = (const float*)d_in[9];
    const float* bo    = (const float*)d_in[10];
    const float* w1    = (const float*)d_in[11];
    const float* b1    = (const float*)d_in[12];
    const float* w2    = (const float*)d_in[13];
    const float* b2    = (const float*)d_in[14];
    const float* ln2_g = (const float*)d_in[15];
    const float* ln2_b = (const float*)d_in[16];
    float* out = (float*)d_out;

    char* w = (char*)d_ws;
    const size_t MB = 1024 * 1024;
    u16*   wqkvt = (u16*)(w + 0);        // [0,6) MB
    u16*   wot   = (u16*)(w + 6  * MB);  // [6,8)
    u16*   w1t   = (u16*)(w + 8  * MB);  // [8,16)
    u16*   w2t   = (u16*)(w + 16 * MB);  // [16,24)
    u16*   h1    = (u16*)(w + 24 * MB);  // [24,32): ln1 / attn-out / ln2
    u16*   qkvb  = (u16*)(w + 32 * MB);  // [32,56): Q|K|V (bh,s,d)
    u16*   vtb   = (u16*)(w + 56 * MB);  // [56,64): V^T (bh,d,s)
    float* x1    = (float*)(w + 64 * MB);// [64,80): fp32 residual-1
    float* part1 = (float*)(w + 80 * MB);// [80,96): FF2 split-K partial z=1
    u16*   ffb   = (u16*)(w + 32 * MB);  // [32,64): FF hidden (reuses qkv/vtb)
    u16*   qb = qkvb;
    u16*   kb = qkvb + 4194304;
    u16*   vb = qkvb + 8388608;

    transpose_cvt4<<<dim3(32, 32, 4), 256, 0, stream>>>(
        wq, wk, wv, wo, wqkvt, wqkvt + 1048576, wqkvt + 2097152, wot);
    transpose_cvt<<<dim3(128, 32), 256, 0, stream>>>(w1, w1t, 1024, 4096);
    transpose_cvt<<<dim3(32, 128), 256, 0, stream>>>(w2, w2t, 4096, 1024);

    ln_kernel<<<4096, 256, 0, stream>>>(x, ln1_g, ln1_b, h1);

    // QKV: 4096x3072, K=1024. 256^2 tiles -> 192 blocks (3x8 per XCD).
    gemm256_kernel<0><<<dim3(12, 16), 512, 0, stream>>>(
        h1, wqkvt, bq, bk, bv, qkvb, 1024, 3072);

    vtrans_kernel<<<dim3(32, 32), 256, 0, stream>>>(vb, vtb);

    attn_kernel<<<dim3(512), 512, 0, stream>>>(qb, kb, vtb, h1);

    // O-proj: 4096x1024, K=1024. 128x64 single-buffer, high TLP.
    gemm_oproj_kernel<<<dim3(16, 32), 256, 0, stream>>>(
        h1, wot, bo, x, x1, 1024, 1024);

    ln_kernel<<<4096, 256, 0, stream>>>(x1, ln2_g, ln2_b, h1);

    // FF1: 4096x4096, K=1024. 256 blocks = 1/CU (4x8 per XCD).
    gemm256_kernel<2><<<dim3(16, 16), 512, 0, stream>>>(
        h1, w1t, b1, nullptr, nullptr, ffb, 1024, 4096);

    // FF2: 4096x1024, K=4096. 128^2 8-wave dbuf split-K=2 -> 512 blocks.
    gemm_ff2_kernel<<<dim3(8, 32, 2), 512, 0, stream>>>(
        ffb, w2t, b2, x1, part1, out, 4096, 1024);

    add_kernel<<<4096, 256, 0, stream>>>(out, part1);
}